// Round 1
// baseline (478.199 us; speedup 1.0000x reference)
//
#include <hip/hip_runtime.h>
#include <stdint.h>

typedef __bf16 bf16_t;
typedef __bf16 bf16x8 __attribute__((ext_vector_type(8)));
typedef float f32x4 __attribute__((ext_vector_type(4)));

typedef const __attribute__((address_space(1))) void gv_t;
typedef __attribute__((address_space(3))) void lv_t;

#define BM 128
#define BN 128
#define BK 32

// Stage a 128x32 bf16 tile (8 KB) row-major into LDS via global_load_lds.
// Per wave: 2 issues of 1024 B (lane*16 within each). LDS dest is wave-uniform
// base; HW scatters lane i at base + i*16 (linear layout requirement, m104).
__device__ __forceinline__ void stage_tile(const bf16_t* g, int ldg,
                                           bf16_t* lds, int wave, int lane) {
#pragma unroll
  for (int i = 0; i < 2; ++i) {
    int off = i * 4096 + wave * 1024 + lane * 16;  // byte offset within tile
    int row = off >> 6;                             // 64 B per row (32 bf16)
    int colb = off & 63;
    const char* src = (const char*)g + (size_t)row * ((size_t)ldg * 2) + colb;
    bf16_t* dst = lds + ((i * 4096 + wave * 1024) >> 1);
    __builtin_amdgcn_global_load_lds((gv_t*)src, (lv_t*)dst, 16, 0, 0);
  }
}

// B^T-input GEMM: C[M,N] = A[M,K] * Bt[N,K]^T. 128x128 tile, BK=32, 4 waves,
// each wave owns a 64x64 subtile = 4x4 frags of 16x16, mfma_f32_16x16x32_bf16.
// EPI 0: f32 C. EPI 1: bf16 C. EPI 2: QKV epilogue (q,k row-major; v transposed).
template <int EPI>
__global__ __launch_bounds__(256) void gemm_bt(
    const bf16_t* __restrict__ A, const bf16_t* __restrict__ Bt,
    float* __restrict__ Cf, bf16_t* __restrict__ Cb,
    bf16_t* __restrict__ qo, bf16_t* __restrict__ ko, bf16_t* __restrict__ vt,
    int M, int N, int K) {
  __shared__ bf16_t lA[2][BM * BK];
  __shared__ bf16_t lB[2][BN * BK];

  const int tid = threadIdx.x;
  const int wave = tid >> 6;
  const int lane = tid & 63;

  const int ntN = N / BN;
  const int nwg = gridDim.x;
  int bid = blockIdx.x;
  // XCD-aware bijective swizzle (valid since nwg % 8 == 0 for all our launches)
  if ((nwg & 7) == 0) bid = (bid & 7) * (nwg >> 3) + (bid >> 3);
  const int tm = bid / ntN;
  const int tn = bid % ntN;

  const bf16_t* Ab = A + (size_t)tm * BM * K;
  const bf16_t* Bb = Bt + (size_t)tn * BN * K;

  f32x4 acc[4][4];
#pragma unroll
  for (int m = 0; m < 4; ++m)
#pragma unroll
    for (int n = 0; n < 4; ++n) acc[m][n] = (f32x4){0.f, 0.f, 0.f, 0.f};

  const int wr = (wave >> 1) * 64;  // wave row offset in tile
  const int wc = (wave & 1) * 64;   // wave col offset in tile
  const int fr = lane & 15;
  const int kr = (lane >> 4) * 8;

  const int nk = K / BK;
  stage_tile(Ab, K, &lA[0][0], wave, lane);
  stage_tile(Bb, K, &lB[0][0], wave, lane);
  __syncthreads();

  for (int kt = 0; kt < nk; ++kt) {
    const int cur = kt & 1;
    if (kt + 1 < nk) {
      stage_tile(Ab + (size_t)(kt + 1) * BK, K, &lA[cur ^ 1][0], wave, lane);
      stage_tile(Bb + (size_t)(kt + 1) * BK, K, &lB[cur ^ 1][0], wave, lane);
    }
    bf16x8 a[4], b[4];
#pragma unroll
    for (int m = 0; m < 4; ++m)
      a[m] = *(const bf16x8*)&lA[cur][(wr + m * 16 + fr) * BK + kr];
#pragma unroll
    for (int n = 0; n < 4; ++n)
      b[n] = *(const bf16x8*)&lB[cur][(wc + n * 16 + fr) * BK + kr];
#pragma unroll
    for (int m = 0; m < 4; ++m)
#pragma unroll
      for (int n = 0; n < 4; ++n)
        acc[m][n] =
            __builtin_amdgcn_mfma_f32_16x16x32_bf16(a[m], b[n], acc[m][n], 0, 0, 0);
    __syncthreads();  // drains vmcnt (stage) + lgkmcnt (ds_read) per compiler
  }

  // C/D frag mapping (m89-verified): col = lane&15, row = (lane>>4)*4 + reg
  const int fro = (lane >> 4) * 4;
#pragma unroll
  for (int m = 0; m < 4; ++m) {
#pragma unroll
    for (int n = 0; n < 4; ++n) {
      const int row = tm * BM + wr + m * 16 + fro;
      const int col = tn * BN + wc + n * 16 + fr;
      if (EPI == 0) {
#pragma unroll
        for (int j = 0; j < 4; ++j)
          Cf[(size_t)(row + j) * N + col] = acc[m][n][j];
      } else if (EPI == 1) {
#pragma unroll
        for (int j = 0; j < 4; ++j)
          Cb[(size_t)(row + j) * N + col] = (bf16_t)acc[m][n][j];
      } else {
        // QKV: N==3072. 128-col tiles never straddle the 1024/2048 boundaries.
        if (col < 1024) {
#pragma unroll
          for (int j = 0; j < 4; ++j)
            qo[(size_t)(row + j) * 1024 + col] = (bf16_t)acc[m][n][j];
        } else if (col < 2048) {
#pragma unroll
          for (int j = 0; j < 4; ++j)
            ko[(size_t)(row + j) * 1024 + (col - 1024)] = (bf16_t)acc[m][n][j];
        } else {
          // v transposed: vt[d][n], rows row..row+3 contiguous -> 8 B store
          union {
            bf16_t h[4];
            uint2 u;
          } t;
#pragma unroll
          for (int j = 0; j < 4; ++j) t.h[j] = (bf16_t)acc[m][n][j];
          *(uint2*)&vt[(size_t)(col - 2048) * M + row] = t.u;
        }
      }
    }
  }
}

__global__ __launch_bounds__(256) void cvt_f32_bf16(const float* __restrict__ s,
                                                    bf16_t* __restrict__ d,
                                                    int n8, float scale) {
  int i = blockIdx.x * 256 + threadIdx.x;
  if (i >= n8) return;
  const float4* sp = (const float4*)s + (size_t)i * 2;
  float4 x0 = sp[0], x1 = sp[1];
  bf16x8 o;
  o[0] = (bf16_t)(x0.x * scale);
  o[1] = (bf16_t)(x0.y * scale);
  o[2] = (bf16_t)(x0.z * scale);
  o[3] = (bf16_t)(x0.w * scale);
  o[4] = (bf16_t)(x1.x * scale);
  o[5] = (bf16_t)(x1.y * scale);
  o[6] = (bf16_t)(x1.z * scale);
  o[7] = (bf16_t)(x1.w * scale);
  ((bf16x8*)d)[i] = o;
}

// In-place row softmax on bf16 [rows][C], C == 8192, one block per row.
__global__ __launch_bounds__(256) void softmax_rows(bf16_t* __restrict__ S, int C) {
  const size_t row = blockIdx.x;
  bf16_t* p = S + row * (size_t)C;
  const int tid = threadIdx.x;
  const int wave = tid >> 6;
  const int lane = tid & 63;

  float v[32];
#pragma unroll
  for (int i = 0; i < 4; ++i) {
    bf16x8 x = ((const bf16x8*)p)[i * 256 + tid];
#pragma unroll
    for (int j = 0; j < 8; ++j) v[i * 8 + j] = (float)x[j];
  }
  float mx = v[0];
#pragma unroll
  for (int i = 1; i < 32; ++i) mx = fmaxf(mx, v[i]);
#pragma unroll
  for (int off = 1; off < 64; off <<= 1) mx = fmaxf(mx, __shfl_xor(mx, off, 64));
  __shared__ float smx[4], ssm[4];
  if (lane == 0) smx[wave] = mx;
  __syncthreads();
  mx = fmaxf(fmaxf(smx[0], smx[1]), fmaxf(smx[2], smx[3]));

  float s = 0.f;
#pragma unroll
  for (int i = 0; i < 32; ++i) {
    v[i] = __expf(v[i] - mx);
    s += v[i];
  }
#pragma unroll
  for (int off = 1; off < 64; off <<= 1) s += __shfl_xor(s, off, 64);
  if (lane == 0) ssm[wave] = s;
  __syncthreads();
  s = ssm[0] + ssm[1] + ssm[2] + ssm[3];
  const float r = 1.0f / s;
#pragma unroll
  for (int i = 0; i < 4; ++i) {
    bf16x8 o;
#pragma unroll
    for (int j = 0; j < 8; ++j) o[j] = (bf16_t)(v[i * 8 + j] * r);
    ((bf16x8*)p)[i * 256 + tid] = o;
  }
}

extern "C" void kernel_launch(void* const* d_in, const int* in_sizes, int n_in,
                              void* d_out, int out_size, void* d_ws, size_t ws_size,
                              hipStream_t stream) {
  const int N = 8192, D = 1024;
  const float* x = (const float*)d_in[0];
  const float* Wq = (const float*)d_in[1];
  const float* Wk = (const float*)d_in[2];
  const float* Wv = (const float*)d_in[3];
  float* out = (float*)d_out;

  // Workspace layout (176 MB total):
  //   [0,16)    qb   bf16 [8192,1024]
  //   [16,32)   kb   bf16 [8192,1024]
  //   [32,48)   vt   bf16 [1024,8192]  (V^T)
  //   [48,176)  S    bf16 [8192,8192]
  //   xb (16 MB) and Wb (6 MB) live INSIDE the S region (dead before S written)
  bf16_t* qb = (bf16_t*)d_ws;
  bf16_t* kb = qb + (size_t)N * D;
  bf16_t* vt = kb + (size_t)N * D;
  bf16_t* S = vt + (size_t)N * D;
  bf16_t* xb = S;                       // aliases start of S region
  bf16_t* Wb = xb + (size_t)N * D;      // 3*D*D bf16 right after xb

  // 1) fp32 -> bf16 converts (1/sqrt(D)=1/32 folded into Wq)
  cvt_f32_bf16<<<(N * D / 8) / 256, 256, 0, stream>>>(x, xb, N * D / 8, 1.0f);
  cvt_f32_bf16<<<(D * D / 8) / 256, 256, 0, stream>>>(Wq, Wb, D * D / 8, 0.03125f);
  cvt_f32_bf16<<<(D * D / 8) / 256, 256, 0, stream>>>(Wk, Wb + (size_t)D * D,
                                                      D * D / 8, 1.0f);
  cvt_f32_bf16<<<(D * D / 8) / 256, 256, 0, stream>>>(Wv, Wb + (size_t)2 * D * D,
                                                      D * D / 8, 1.0f);

  // 2) fused QKV GEMM: [8192,1024] x [3072,1024]^T -> qb, kb, vt(V^T)
  gemm_bt<2><<<(N / BM) * (3 * D / BN), 256, 0, stream>>>(
      xb, Wb, nullptr, nullptr, qb, kb, vt, N, 3 * D, D);

  // 3) scores: qb @ kb^T -> S (bf16, already scaled via Wq)
  gemm_bt<1><<<(N / BM) * (N / BN), 256, 0, stream>>>(
      qb, kb, nullptr, S, nullptr, nullptr, nullptr, N, N, D);

  // 4) row softmax in place on S
  softmax_rows<<<N, 256, 0, stream>>>(S, N);

  // 5) out = P @ V = S @ vt^T -> f32 d_out
  gemm_bt<0><<<(N / BM) * (D / BN), 256, 0, stream>>>(
      S, vt, out, nullptr, nullptr, nullptr, nullptr, N, D, N);
}

// Round 2
// 435.952 us; speedup vs baseline: 1.0969x; 1.0969x over previous
//
#include <hip/hip_runtime.h>
#include <stdint.h>

typedef __bf16 bf16_t;
typedef __bf16 bf16x8 __attribute__((ext_vector_type(8)));
typedef float f32x4 __attribute__((ext_vector_type(4)));

typedef const __attribute__((address_space(1))) void gv_t;
typedef __attribute__((address_space(3))) void lv_t;

// ======================= old 128x128 m97-structure GEMM =======================
#define BM 128
#define BN 128
#define BK 32

__device__ __forceinline__ void stage_tile(const bf16_t* g, int ldg,
                                           bf16_t* lds, int wave, int lane) {
#pragma unroll
  for (int i = 0; i < 2; ++i) {
    int off = i * 4096 + wave * 1024 + lane * 16;
    int row = off >> 6;
    int colb = off & 63;
    const char* src = (const char*)g + (size_t)row * ((size_t)ldg * 2) + colb;
    bf16_t* dst = lds + ((i * 4096 + wave * 1024) >> 1);
    __builtin_amdgcn_global_load_lds((gv_t*)src, (lv_t*)dst, 16, 0, 0);
  }
}

// B^T-input GEMM: C[M,N] = A[M,K] * Bt[N,K]^T. Used for PV only (EPI 0, f32 C).
template <int EPI>
__global__ __launch_bounds__(256) void gemm_bt(
    const bf16_t* __restrict__ A, const bf16_t* __restrict__ Bt,
    float* __restrict__ Cf, int M, int N, int K) {
  __shared__ bf16_t lA[2][BM * BK];
  __shared__ bf16_t lB[2][BN * BK];

  const int tid = threadIdx.x;
  const int wave = tid >> 6;
  const int lane = tid & 63;

  const int ntN = N / BN;
  const int nwg = gridDim.x;
  int bid = blockIdx.x;
  if ((nwg & 7) == 0) bid = (bid & 7) * (nwg >> 3) + (bid >> 3);
  const int tm = bid / ntN;
  const int tn = bid % ntN;

  const bf16_t* Ab = A + (size_t)tm * BM * K;
  const bf16_t* Bb = Bt + (size_t)tn * BN * K;

  f32x4 acc[4][4];
#pragma unroll
  for (int m = 0; m < 4; ++m)
#pragma unroll
    for (int n = 0; n < 4; ++n) acc[m][n] = (f32x4){0.f, 0.f, 0.f, 0.f};

  const int wr = (wave >> 1) * 64;
  const int wc = (wave & 1) * 64;
  const int fr = lane & 15;
  const int kr = (lane >> 4) * 8;

  const int nk = K / BK;
  stage_tile(Ab, K, &lA[0][0], wave, lane);
  stage_tile(Bb, K, &lB[0][0], wave, lane);
  __syncthreads();

  for (int kt = 0; kt < nk; ++kt) {
    const int cur = kt & 1;
    if (kt + 1 < nk) {
      stage_tile(Ab + (size_t)(kt + 1) * BK, K, &lA[cur ^ 1][0], wave, lane);
      stage_tile(Bb + (size_t)(kt + 1) * BK, K, &lB[cur ^ 1][0], wave, lane);
    }
    bf16x8 a[4], b[4];
#pragma unroll
    for (int m = 0; m < 4; ++m)
      a[m] = *(const bf16x8*)&lA[cur][(wr + m * 16 + fr) * BK + kr];
#pragma unroll
    for (int n = 0; n < 4; ++n)
      b[n] = *(const bf16x8*)&lB[cur][(wc + n * 16 + fr) * BK + kr];
#pragma unroll
    for (int m = 0; m < 4; ++m)
#pragma unroll
      for (int n = 0; n < 4; ++n)
        acc[m][n] =
            __builtin_amdgcn_mfma_f32_16x16x32_bf16(a[m], b[n], acc[m][n], 0, 0, 0);
    __syncthreads();
  }

  const int fro = (lane >> 4) * 4;
#pragma unroll
  for (int m = 0; m < 4; ++m) {
#pragma unroll
    for (int n = 0; n < 4; ++n) {
      const int row = tm * BM + wr + m * 16 + fro;
      const int col = tn * BN + wc + n * 16 + fr;
#pragma unroll
      for (int j = 0; j < 4; ++j)
        Cf[(size_t)(row + j) * N + col] = acc[m][n][j];
    }
  }
}

// ======================= 256x256 8-phase GEMM (T2+T3+T4+T5) =======================
// BK=64, 8 waves (2Mx4N), per-wave 128x64 out split into 4 quadrants of 64x32.
// LDS: 2 bufs x {A0,A1,B0,B1} halves of [128 rows][64 k] bf16 (16 KB each) = 128 KB.
// Swizzle: byte ^= (row&7)<<4 on ds_read; inverse-swizzled global src for
// global_load_lds (linear LDS dest, rule #21).

__device__ __forceinline__ void stage_half2(const bf16_t* g, int K, bf16_t* lh,
                                            int wave, int lane) {
#pragma unroll
  for (int i = 0; i < 2; ++i) {
    const int ub = i * 8192 + wave * 1024;       // wave-uniform LDS byte base
    const int o = ub + lane * 16;                // this lane's linear LDS byte
    const int row = o >> 7;                      // 128 B per row
    const int kb = (o & 127) ^ ((row & 7) << 4); // inverse swizzle on source
    const char* src = (const char*)g + (size_t)row * ((size_t)K * 2) + kb;
    __builtin_amdgcn_global_load_lds((gv_t*)src, (lv_t*)(lh + (ub >> 1)), 16, 0, 0);
  }
}

__device__ __forceinline__ bf16x8 ld_frag2(const bf16_t* h, int r, int s, int lane) {
  int byte = r * 128 + s * 64 + ((lane >> 4) << 4);
  byte ^= (r & 7) << 4;
  return *(const bf16x8*)((const char*)h + byte);
}

// EPI 1: bf16 C (scores). EPI 2: QKV epilogue (q,k row-major; v transposed).
template <int EPI>
__global__ __launch_bounds__(512) void gemm8p(
    const bf16_t* __restrict__ A, const bf16_t* __restrict__ Bt,
    bf16_t* __restrict__ Cb, bf16_t* __restrict__ qo, bf16_t* __restrict__ ko,
    bf16_t* __restrict__ vtb, int M, int N, int K) {
  __shared__ __align__(16) bf16_t L[2][4][8192];  // [buf][A0,A1,B0,B1][128*64]

  const int tid = threadIdx.x;
  const int wave = tid >> 6;
  const int lane = tid & 63;

  const int ntN = N >> 8;
  const int nwg = gridDim.x;
  int bid = blockIdx.x;
  bid = (bid & 7) * (nwg >> 3) + (bid >> 3);  // all grids here are %8==0
  const int tm = bid / ntN;
  const int tn = bid % ntN;

  const bf16_t* Ab = A + (size_t)tm * 256 * K;
  const bf16_t* Bb = Bt + (size_t)tn * 256 * K;

  const int wr64 = (wave >> 2) * 64;  // row base within each 128-row half
  const int wc32 = (wave & 3) * 32;   // col base within each 128-col half
  const int fr = lane & 15;
  const int nt = K >> 6;

  f32x4 acc00[4][2], acc01[4][2], acc10[4][2], acc11[4][2];
#pragma unroll
  for (int m = 0; m < 4; ++m)
#pragma unroll
    for (int n = 0; n < 2; ++n) {
      acc00[m][n] = (f32x4){0.f, 0.f, 0.f, 0.f};
      acc01[m][n] = (f32x4){0.f, 0.f, 0.f, 0.f};
      acc10[m][n] = (f32x4){0.f, 0.f, 0.f, 0.f};
      acc11[m][n] = (f32x4){0.f, 0.f, 0.f, 0.f};
    }

  // Prologue: tile0 fully + {A0,B1} of tile1 (12 loads); drain tile0, keep 4.
  stage_half2(Ab, K, &L[0][0][0], wave, lane);
  stage_half2(Ab + (size_t)128 * K, K, &L[0][1][0], wave, lane);
  stage_half2(Bb, K, &L[0][2][0], wave, lane);
  stage_half2(Bb + (size_t)128 * K, K, &L[0][3][0], wave, lane);
  stage_half2(Ab + 64, K, &L[1][0][0], wave, lane);
  stage_half2(Bb + (size_t)128 * K + 64, K, &L[1][3][0], wave, lane);
  asm volatile("s_waitcnt vmcnt(4)" ::: "memory");
  __builtin_amdgcn_s_barrier();

  bf16x8 a[4][2], bA[2][2], bB[2][2];

  for (int t = 0; t < nt; ++t) {
    const int cur = t & 1;
    const bf16_t* A0h = &L[cur][0][0];
    const bf16_t* A1h = &L[cur][1][0];
    const bf16_t* B0h = &L[cur][2][0];
    const bf16_t* B1h = &L[cur][3][0];

    // -- phase 1: quadrant (qm0,qn0); stage A1(t+1)
#pragma unroll
    for (int m = 0; m < 4; ++m)
#pragma unroll
      for (int s = 0; s < 2; ++s)
        a[m][s] = ld_frag2(A0h, wr64 + m * 16 + fr, s, lane);
#pragma unroll
    for (int n = 0; n < 2; ++n)
#pragma unroll
      for (int s = 0; s < 2; ++s)
        bA[n][s] = ld_frag2(B0h, wc32 + n * 16 + fr, s, lane);
    if (t + 1 < nt)
      stage_half2(Ab + (size_t)128 * K + (size_t)(t + 1) * 64, K, &L[cur ^ 1][1][0],
                  wave, lane);
    __builtin_amdgcn_s_barrier();
    __builtin_amdgcn_s_setprio(1);
#pragma unroll
    for (int s = 0; s < 2; ++s)
#pragma unroll
      for (int m = 0; m < 4; ++m)
#pragma unroll
        for (int n = 0; n < 2; ++n)
          acc00[m][n] = __builtin_amdgcn_mfma_f32_16x16x32_bf16(a[m][s], bA[n][s],
                                                                acc00[m][n], 0, 0, 0);
    __builtin_amdgcn_s_setprio(0);
    __builtin_amdgcn_s_barrier();

    // -- phase 2: quadrant (qm0,qn1); stage B0(t+1)
#pragma unroll
    for (int n = 0; n < 2; ++n)
#pragma unroll
      for (int s = 0; s < 2; ++s)
        bB[n][s] = ld_frag2(B1h, wc32 + n * 16 + fr, s, lane);
    if (t + 1 < nt)
      stage_half2(Bb + (size_t)(t + 1) * 64, K, &L[cur ^ 1][2][0], wave, lane);
    __builtin_amdgcn_s_barrier();
    __builtin_amdgcn_s_setprio(1);
#pragma unroll
    for (int s = 0; s < 2; ++s)
#pragma unroll
      for (int m = 0; m < 4; ++m)
#pragma unroll
        for (int n = 0; n < 2; ++n)
          acc01[m][n] = __builtin_amdgcn_mfma_f32_16x16x32_bf16(a[m][s], bB[n][s],
                                                                acc01[m][n], 0, 0, 0);
    __builtin_amdgcn_s_setprio(0);
    __builtin_amdgcn_s_barrier();

    // -- phase 3: quadrant (qm1,qn1); stage A0(t+2)
#pragma unroll
    for (int m = 0; m < 4; ++m)
#pragma unroll
      for (int s = 0; s < 2; ++s)
        a[m][s] = ld_frag2(A1h, wr64 + m * 16 + fr, s, lane);
    if (t + 2 < nt)
      stage_half2(Ab + (size_t)(t + 2) * 64, K, &L[cur][0][0], wave, lane);
    __builtin_amdgcn_s_barrier();
    __builtin_amdgcn_s_setprio(1);
#pragma unroll
    for (int s = 0; s < 2; ++s)
#pragma unroll
      for (int m = 0; m < 4; ++m)
#pragma unroll
        for (int n = 0; n < 2; ++n)
          acc11[m][n] = __builtin_amdgcn_mfma_f32_16x16x32_bf16(a[m][s], bB[n][s],
                                                                acc11[m][n], 0, 0, 0);
    __builtin_amdgcn_s_setprio(0);
    __builtin_amdgcn_s_barrier();

    // -- phase 4: quadrant (qm1,qn0); stage B1(t+2); boundary counted-vmcnt
    if (t + 2 < nt)
      stage_half2(Bb + (size_t)128 * K + (size_t)(t + 2) * 64, K, &L[cur][3][0],
                  wave, lane);
    __builtin_amdgcn_s_barrier();
    __builtin_amdgcn_s_setprio(1);
#pragma unroll
    for (int s = 0; s < 2; ++s)
#pragma unroll
      for (int m = 0; m < 4; ++m)
#pragma unroll
        for (int n = 0; n < 2; ++n)
          acc10[m][n] = __builtin_amdgcn_mfma_f32_16x16x32_bf16(a[m][s], bA[n][s],
                                                                acc10[m][n], 0, 0, 0);
    __builtin_amdgcn_s_setprio(0);
    // Drain everything of tile t+1; keep t+2's {A0,B1} (4 loads) in flight.
    if (t + 2 < nt)
      asm volatile("s_waitcnt vmcnt(4)" ::: "memory");
    else
      asm volatile("s_waitcnt vmcnt(0)" ::: "memory");
    __builtin_amdgcn_s_barrier();
  }

  // Epilogue. C/D mapping: col = lane&15, row = (lane>>4)*4 + j (m89-verified).
  const int fro = (lane >> 4) * 4;
#define STORE_QUAD(ACC, QM, QN)                                                  \
  _Pragma("unroll") for (int m = 0; m < 4; ++m) {                                \
    _Pragma("unroll") for (int n = 0; n < 2; ++n) {                              \
      const int row = tm * 256 + QM * 128 + wr64 + m * 16 + fro;                 \
      const int col = tn * 256 + QN * 128 + wc32 + n * 16 + fr;                  \
      if (EPI == 1) {                                                            \
        _Pragma("unroll") for (int j = 0; j < 4; ++j)                            \
            Cb[(size_t)(row + j) * N + col] = (bf16_t)ACC[m][n][j];              \
      } else {                                                                   \
        if (col < 1024) {                                                        \
          _Pragma("unroll") for (int j = 0; j < 4; ++j)                          \
              qo[(size_t)(row + j) * 1024 + col] = (bf16_t)ACC[m][n][j];         \
        } else if (col < 2048) {                                                 \
          _Pragma("unroll") for (int j = 0; j < 4; ++j)                          \
              ko[(size_t)(row + j) * 1024 + (col - 1024)] = (bf16_t)ACC[m][n][j];\
        } else {                                                                 \
          union { bf16_t h[4]; uint2 u; } tpk;                                   \
          _Pragma("unroll") for (int j = 0; j < 4; ++j)                          \
              tpk.h[j] = (bf16_t)ACC[m][n][j];                                   \
          *(uint2*)&vtb[(size_t)(col - 2048) * M + row] = tpk.u;                 \
        }                                                                        \
      }                                                                          \
    }                                                                            \
  }
  STORE_QUAD(acc00, 0, 0)
  STORE_QUAD(acc01, 0, 1)
  STORE_QUAD(acc10, 1, 0)
  STORE_QUAD(acc11, 1, 1)
#undef STORE_QUAD
}

// ======================= converts & softmax =======================
__global__ __launch_bounds__(256) void cvt_f32_bf16(const float* __restrict__ s,
                                                    bf16_t* __restrict__ d,
                                                    int n8, float scale) {
  int i = blockIdx.x * 256 + threadIdx.x;
  if (i >= n8) return;
  const float4* sp = (const float4*)s + (size_t)i * 2;
  float4 x0 = sp[0], x1 = sp[1];
  bf16x8 o;
  o[0] = (bf16_t)(x0.x * scale);
  o[1] = (bf16_t)(x0.y * scale);
  o[2] = (bf16_t)(x0.z * scale);
  o[3] = (bf16_t)(x0.w * scale);
  o[4] = (bf16_t)(x1.x * scale);
  o[5] = (bf16_t)(x1.y * scale);
  o[6] = (bf16_t)(x1.z * scale);
  o[7] = (bf16_t)(x1.w * scale);
  ((bf16x8*)d)[i] = o;
}

__global__ __launch_bounds__(256) void softmax_rows(bf16_t* __restrict__ S, int C) {
  const size_t row = blockIdx.x;
  bf16_t* p = S + row * (size_t)C;
  const int tid = threadIdx.x;
  const int wave = tid >> 6;
  const int lane = tid & 63;

  float v[32];
#pragma unroll
  for (int i = 0; i < 4; ++i) {
    bf16x8 x = ((const bf16x8*)p)[i * 256 + tid];
#pragma unroll
    for (int j = 0; j < 8; ++j) v[i * 8 + j] = (float)x[j];
  }
  float mx = v[0];
#pragma unroll
  for (int i = 1; i < 32; ++i) mx = fmaxf(mx, v[i]);
#pragma unroll
  for (int off = 1; off < 64; off <<= 1) mx = fmaxf(mx, __shfl_xor(mx, off, 64));
  __shared__ float smx[4], ssm[4];
  if (lane == 0) smx[wave] = mx;
  __syncthreads();
  mx = fmaxf(fmaxf(smx[0], smx[1]), fmaxf(smx[2], smx[3]));

  float s = 0.f;
#pragma unroll
  for (int i = 0; i < 32; ++i) {
    v[i] = __expf(v[i] - mx);
    s += v[i];
  }
#pragma unroll
  for (int off = 1; off < 64; off <<= 1) s += __shfl_xor(s, off, 64);
  if (lane == 0) ssm[wave] = s;
  __syncthreads();
  s = ssm[0] + ssm[1] + ssm[2] + ssm[3];
  const float r = 1.0f / s;
#pragma unroll
  for (int i = 0; i < 4; ++i) {
    bf16x8 o;
#pragma unroll
    for (int j = 0; j < 8; ++j) o[j] = (bf16_t)(v[i * 8 + j] * r);
    ((bf16x8*)p)[i * 256 + tid] = o;
  }
}

extern "C" void kernel_launch(void* const* d_in, const int* in_sizes, int n_in,
                              void* d_out, int out_size, void* d_ws, size_t ws_size,
                              hipStream_t stream) {
  const int N = 8192, D = 1024;
  const float* x = (const float*)d_in[0];
  const float* Wq = (const float*)d_in[1];
  const float* Wk = (const float*)d_in[2];
  const float* Wv = (const float*)d_in[3];
  float* out = (float*)d_out;

  bf16_t* qb = (bf16_t*)d_ws;
  bf16_t* kb = qb + (size_t)N * D;
  bf16_t* vt = kb + (size_t)N * D;
  bf16_t* S = vt + (size_t)N * D;
  bf16_t* xb = S;                   // aliases start of S region (dead until S written)
  bf16_t* Wb = xb + (size_t)N * D;  // 3*D*D bf16 right after xb

  // 1) fp32 -> bf16 converts (1/sqrt(D)=1/32 folded into Wq)
  cvt_f32_bf16<<<(N * D / 8) / 256, 256, 0, stream>>>(x, xb, N * D / 8, 1.0f);
  cvt_f32_bf16<<<(D * D / 8) / 256, 256, 0, stream>>>(Wq, Wb, D * D / 8, 0.03125f);
  cvt_f32_bf16<<<(D * D / 8) / 256, 256, 0, stream>>>(Wk, Wb + (size_t)D * D,
                                                      D * D / 8, 1.0f);
  cvt_f32_bf16<<<(D * D / 8) / 256, 256, 0, stream>>>(Wv, Wb + (size_t)2 * D * D,
                                                      D * D / 8, 1.0f);

  // 2) fused QKV (8-phase 256^2): [8192,1024] x [3072,1024]^T -> qb, kb, vt(V^T)
  gemm8p<2><<<(N / 256) * (3 * D / 256), 512, 0, stream>>>(
      xb, Wb, nullptr, qb, kb, vt, N, 3 * D, D);

  // 3) scores (8-phase 256^2): qb @ kb^T -> S bf16 (scale folded into Wq)
  gemm8p<1><<<(N / 256) * (N / 256), 512, 0, stream>>>(
      qb, kb, S, nullptr, nullptr, nullptr, N, N, D);

  // 4) row softmax in place on S
  softmax_rows<<<N, 256, 0, stream>>>(S, N);

  // 5) out = P @ V = S @ vt^T -> f32 d_out (old 128^2 path)
  gemm_bt<0><<<(N / BM) * (D / BN), 256, 0, stream>>>(S, vt, out, N, D, N);
}

// Round 3
// 408.045 us; speedup vs baseline: 1.1719x; 1.0684x over previous
//
#include <hip/hip_runtime.h>
#include <stdint.h>

typedef __bf16 bf16_t;
typedef __bf16 bf16x8 __attribute__((ext_vector_type(8)));
typedef float f32x4 __attribute__((ext_vector_type(4)));

typedef const __attribute__((address_space(1))) void gv_t;
typedef __attribute__((address_space(3))) void lv_t;

// ======================= 256x256 8-phase GEMM (T1+T2+T3+T4+T5) ====================
// BK=64, 8 waves (2Mx4N), per-wave 128x64 out split into 4 quadrants of 64x32.
// LDS: 2 bufs x {A0,A1,B0,B1} halves of [128 rows][64 k] bf16 (16 KB each) = 128 KB.
// Swizzle: byte ^= (row&7)<<4 on ds_read; inverse-swizzled global src for
// global_load_lds (linear LDS dest, rule #21).
// Split-K: grid = ntM*ntN*nks; ks selects K-slab (extent Kext, row stride ldk)
// and output buffer (Cf0 for ks=0, Cf1 for ks=1).

__device__ __forceinline__ void stage_half2(const bf16_t* g, int ldk, bf16_t* lh,
                                            int wave, int lane) {
#pragma unroll
  for (int i = 0; i < 2; ++i) {
    const int ub = i * 8192 + wave * 1024;       // wave-uniform LDS byte base
    const int o = ub + lane * 16;                // this lane's linear LDS byte
    const int row = o >> 7;                      // 128 B per row
    const int kb = (o & 127) ^ ((row & 7) << 4); // inverse swizzle on source
    const char* src = (const char*)g + (size_t)row * ((size_t)ldk * 2) + kb;
    __builtin_amdgcn_global_load_lds((gv_t*)src, (lv_t*)(lh + (ub >> 1)), 16, 0, 0);
  }
}

__device__ __forceinline__ bf16x8 ld_frag2(const bf16_t* h, int r, int s, int lane) {
  int byte = r * 128 + s * 64 + ((lane >> 4) << 4);
  byte ^= (r & 7) << 4;
  return *(const bf16x8*)((const char*)h + byte);
}

// EPI 0: f32 C (PV, split-K partials). EPI 1: bf16 C (scores).
// EPI 2: QKV epilogue (q,k row-major; v transposed).
template <int EPI>
__global__ __launch_bounds__(512) void gemm8p(
    const bf16_t* __restrict__ A, const bf16_t* __restrict__ Bt,
    bf16_t* __restrict__ Cb, float* __restrict__ Cf0, float* __restrict__ Cf1,
    bf16_t* __restrict__ qo, bf16_t* __restrict__ ko, bf16_t* __restrict__ vtb,
    int M, int N, int Kext, int ldk, int nks) {
  __shared__ __align__(16) bf16_t L[2][4][8192];  // [buf][A0,A1,B0,B1][128*64]

  const int tid = threadIdx.x;
  const int wave = tid >> 6;
  const int lane = tid & 63;

  const int ntN = N >> 8;
  const int ntM = M >> 8;
  const int nwg = gridDim.x;
  int bid = blockIdx.x;
  bid = (bid & 7) * (nwg >> 3) + (bid >> 3);  // XCD swizzle; all grids %8==0
  const int ks = bid / (ntM * ntN);
  const int rem = bid % (ntM * ntN);
  const int tm = rem / ntN;
  const int tn = rem % ntN;

  const bf16_t* Ab = A + (size_t)tm * 256 * ldk + (size_t)ks * Kext;
  const bf16_t* Bb = Bt + (size_t)tn * 256 * ldk + (size_t)ks * Kext;
  float* __restrict__ Cf = ks ? Cf1 : Cf0;

  const int wr64 = (wave >> 2) * 64;  // row base within each 128-row half
  const int wc32 = (wave & 3) * 32;   // col base within each 128-col half
  const int fr = lane & 15;
  const int nt = Kext >> 6;

  f32x4 acc00[4][2], acc01[4][2], acc10[4][2], acc11[4][2];
#pragma unroll
  for (int m = 0; m < 4; ++m)
#pragma unroll
    for (int n = 0; n < 2; ++n) {
      acc00[m][n] = (f32x4){0.f, 0.f, 0.f, 0.f};
      acc01[m][n] = (f32x4){0.f, 0.f, 0.f, 0.f};
      acc10[m][n] = (f32x4){0.f, 0.f, 0.f, 0.f};
      acc11[m][n] = (f32x4){0.f, 0.f, 0.f, 0.f};
    }

  // Prologue: tile0 fully + {A0,B1} of tile1 (12 loads); drain tile0, keep 4.
  stage_half2(Ab, ldk, &L[0][0][0], wave, lane);
  stage_half2(Ab + (size_t)128 * ldk, ldk, &L[0][1][0], wave, lane);
  stage_half2(Bb, ldk, &L[0][2][0], wave, lane);
  stage_half2(Bb + (size_t)128 * ldk, ldk, &L[0][3][0], wave, lane);
  stage_half2(Ab + 64, ldk, &L[1][0][0], wave, lane);
  stage_half2(Bb + (size_t)128 * ldk + 64, ldk, &L[1][3][0], wave, lane);
  asm volatile("s_waitcnt vmcnt(4)" ::: "memory");
  __builtin_amdgcn_s_barrier();

  bf16x8 a[4][2], bA[2][2], bB[2][2];

  for (int t = 0; t < nt; ++t) {
    const int cur = t & 1;
    const bf16_t* A0h = &L[cur][0][0];
    const bf16_t* A1h = &L[cur][1][0];
    const bf16_t* B0h = &L[cur][2][0];
    const bf16_t* B1h = &L[cur][3][0];

    // -- phase 1: quadrant (qm0,qn0); stage A1(t+1)
#pragma unroll
    for (int m = 0; m < 4; ++m)
#pragma unroll
      for (int s = 0; s < 2; ++s)
        a[m][s] = ld_frag2(A0h, wr64 + m * 16 + fr, s, lane);
#pragma unroll
    for (int n = 0; n < 2; ++n)
#pragma unroll
      for (int s = 0; s < 2; ++s)
        bA[n][s] = ld_frag2(B0h, wc32 + n * 16 + fr, s, lane);
    if (t + 1 < nt)
      stage_half2(Ab + (size_t)128 * ldk + (size_t)(t + 1) * 64, ldk,
                  &L[cur ^ 1][1][0], wave, lane);
    __builtin_amdgcn_s_barrier();
    __builtin_amdgcn_s_setprio(1);
#pragma unroll
    for (int s = 0; s < 2; ++s)
#pragma unroll
      for (int m = 0; m < 4; ++m)
#pragma unroll
        for (int n = 0; n < 2; ++n)
          acc00[m][n] = __builtin_amdgcn_mfma_f32_16x16x32_bf16(a[m][s], bA[n][s],
                                                                acc00[m][n], 0, 0, 0);
    __builtin_amdgcn_s_setprio(0);
    __builtin_amdgcn_s_barrier();

    // -- phase 2: quadrant (qm0,qn1); stage B0(t+1)
#pragma unroll
    for (int n = 0; n < 2; ++n)
#pragma unroll
      for (int s = 0; s < 2; ++s)
        bB[n][s] = ld_frag2(B1h, wc32 + n * 16 + fr, s, lane);
    if (t + 1 < nt)
      stage_half2(Bb + (size_t)(t + 1) * 64, ldk, &L[cur ^ 1][2][0], wave, lane);
    __builtin_amdgcn_s_barrier();
    __builtin_amdgcn_s_setprio(1);
#pragma unroll
    for (int s = 0; s < 2; ++s)
#pragma unroll
      for (int m = 0; m < 4; ++m)
#pragma unroll
        for (int n = 0; n < 2; ++n)
          acc01[m][n] = __builtin_amdgcn_mfma_f32_16x16x32_bf16(a[m][s], bB[n][s],
                                                                acc01[m][n], 0, 0, 0);
    __builtin_amdgcn_s_setprio(0);
    __builtin_amdgcn_s_barrier();

    // -- phase 3: quadrant (qm1,qn1); stage A0(t+2)
#pragma unroll
    for (int m = 0; m < 4; ++m)
#pragma unroll
      for (int s = 0; s < 2; ++s)
        a[m][s] = ld_frag2(A1h, wr64 + m * 16 + fr, s, lane);
    if (t + 2 < nt)
      stage_half2(Ab + (size_t)(t + 2) * 64, ldk, &L[cur][0][0], wave, lane);
    __builtin_amdgcn_s_barrier();
    __builtin_amdgcn_s_setprio(1);
#pragma unroll
    for (int s = 0; s < 2; ++s)
#pragma unroll
      for (int m = 0; m < 4; ++m)
#pragma unroll
        for (int n = 0; n < 2; ++n)
          acc11[m][n] = __builtin_amdgcn_mfma_f32_16x16x32_bf16(a[m][s], bB[n][s],
                                                                acc11[m][n], 0, 0, 0);
    __builtin_amdgcn_s_setprio(0);
    __builtin_amdgcn_s_barrier();

    // -- phase 4: quadrant (qm1,qn0); stage B1(t+2); boundary counted-vmcnt
    if (t + 2 < nt)
      stage_half2(Bb + (size_t)128 * ldk + (size_t)(t + 2) * 64, ldk, &L[cur][3][0],
                  wave, lane);
    __builtin_amdgcn_s_barrier();
    __builtin_amdgcn_s_setprio(1);
#pragma unroll
    for (int s = 0; s < 2; ++s)
#pragma unroll
      for (int m = 0; m < 4; ++m)
#pragma unroll
        for (int n = 0; n < 2; ++n)
          acc10[m][n] = __builtin_amdgcn_mfma_f32_16x16x32_bf16(a[m][s], bA[n][s],
                                                                acc10[m][n], 0, 0, 0);
    __builtin_amdgcn_s_setprio(0);
    // Drain everything of tile t+1; keep t+2's {A0,B1} (4 loads) in flight.
    if (t + 2 < nt)
      asm volatile("s_waitcnt vmcnt(4)" ::: "memory");
    else
      asm volatile("s_waitcnt vmcnt(0)" ::: "memory");
    __builtin_amdgcn_s_barrier();
  }

  // Epilogue. C/D mapping: col = lane&15, row = (lane>>4)*4 + j (m89-verified).
  const int fro = (lane >> 4) * 4;
#define STORE_QUAD(ACC, QM, QN)                                                  \
  _Pragma("unroll") for (int m = 0; m < 4; ++m) {                                \
    _Pragma("unroll") for (int n = 0; n < 2; ++n) {                              \
      const int row = tm * 256 + QM * 128 + wr64 + m * 16 + fro;                 \
      const int col = tn * 256 + QN * 128 + wc32 + n * 16 + fr;                  \
      if (EPI == 0) {                                                            \
        _Pragma("unroll") for (int j = 0; j < 4; ++j)                            \
            Cf[(size_t)(row + j) * N + col] = ACC[m][n][j];                      \
      } else if (EPI == 1) {                                                     \
        _Pragma("unroll") for (int j = 0; j < 4; ++j)                            \
            Cb[(size_t)(row + j) * N + col] = (bf16_t)ACC[m][n][j];              \
      } else {                                                                   \
        if (col < 1024) {                                                        \
          _Pragma("unroll") for (int j = 0; j < 4; ++j)                          \
              qo[(size_t)(row + j) * 1024 + col] = (bf16_t)ACC[m][n][j];         \
        } else if (col < 2048) {                                                 \
          _Pragma("unroll") for (int j = 0; j < 4; ++j)                          \
              ko[(size_t)(row + j) * 1024 + (col - 1024)] = (bf16_t)ACC[m][n][j];\
        } else {                                                                 \
          union { bf16_t h[4]; uint2 u; } tpk;                                   \
          _Pragma("unroll") for (int j = 0; j < 4; ++j)                          \
              tpk.h[j] = (bf16_t)ACC[m][n][j];                                   \
          *(uint2*)&vtb[(size_t)(col - 2048) * M + row] = tpk.u;                 \
        }                                                                        \
      }                                                                          \
    }                                                                            \
  }
  STORE_QUAD(acc00, 0, 0)
  STORE_QUAD(acc01, 0, 1)
  STORE_QUAD(acc10, 1, 0)
  STORE_QUAD(acc11, 1, 1)
#undef STORE_QUAD
}

// ======================= converts, softmax, reduce-add =======================
__global__ __launch_bounds__(256) void cvt_f32_bf16(const float* __restrict__ s,
                                                    bf16_t* __restrict__ d,
                                                    int n8, float scale) {
  int i = blockIdx.x * 256 + threadIdx.x;
  if (i >= n8) return;
  const float4* sp = (const float4*)s + (size_t)i * 2;
  float4 x0 = sp[0], x1 = sp[1];
  bf16x8 o;
  o[0] = (bf16_t)(x0.x * scale);
  o[1] = (bf16_t)(x0.y * scale);
  o[2] = (bf16_t)(x0.z * scale);
  o[3] = (bf16_t)(x0.w * scale);
  o[4] = (bf16_t)(x1.x * scale);
  o[5] = (bf16_t)(x1.y * scale);
  o[6] = (bf16_t)(x1.z * scale);
  o[7] = (bf16_t)(x1.w * scale);
  ((bf16x8*)d)[i] = o;
}

// out += p1, float4-vectorized
__global__ __launch_bounds__(256) void add_f32x4(float* __restrict__ out,
                                                 const float* __restrict__ p1) {
  size_t i = (size_t)blockIdx.x * 256 + threadIdx.x;
  float4 a = ((const float4*)out)[i];
  float4 b = ((const float4*)p1)[i];
  a.x += b.x;
  a.y += b.y;
  a.z += b.z;
  a.w += b.w;
  ((float4*)out)[i] = a;
}

__global__ __launch_bounds__(256) void softmax_rows(bf16_t* __restrict__ S, int C) {
  const size_t row = blockIdx.x;
  bf16_t* p = S + row * (size_t)C;
  const int tid = threadIdx.x;
  const int wave = tid >> 6;
  const int lane = tid & 63;

  float v[32];
#pragma unroll
  for (int i = 0; i < 4; ++i) {
    bf16x8 x = ((const bf16x8*)p)[i * 256 + tid];
#pragma unroll
    for (int j = 0; j < 8; ++j) v[i * 8 + j] = (float)x[j];
  }
  float mx = v[0];
#pragma unroll
  for (int i = 1; i < 32; ++i) mx = fmaxf(mx, v[i]);
#pragma unroll
  for (int off = 1; off < 64; off <<= 1) mx = fmaxf(mx, __shfl_xor(mx, off, 64));
  __shared__ float smx[4], ssm[4];
  if (lane == 0) smx[wave] = mx;
  __syncthreads();
  mx = fmaxf(fmaxf(smx[0], smx[1]), fmaxf(smx[2], smx[3]));

  float s = 0.f;
#pragma unroll
  for (int i = 0; i < 32; ++i) {
    v[i] = __expf(v[i] - mx);
    s += v[i];
  }
#pragma unroll
  for (int off = 1; off < 64; off <<= 1) s += __shfl_xor(s, off, 64);
  if (lane == 0) ssm[wave] = s;
  __syncthreads();
  s = ssm[0] + ssm[1] + ssm[2] + ssm[3];
  const float r = 1.0f / s;
#pragma unroll
  for (int i = 0; i < 4; ++i) {
    bf16x8 o;
#pragma unroll
    for (int j = 0; j < 8; ++j) o[j] = (bf16_t)(v[i * 8 + j] * r);
    ((bf16x8*)p)[i * 256 + tid] = o;
  }
}

extern "C" void kernel_launch(void* const* d_in, const int* in_sizes, int n_in,
                              void* d_out, int out_size, void* d_ws, size_t ws_size,
                              hipStream_t stream) {
  const int N = 8192, D = 1024;
  const float* x = (const float*)d_in[0];
  const float* Wq = (const float*)d_in[1];
  const float* Wk = (const float*)d_in[2];
  const float* Wv = (const float*)d_in[3];
  float* out = (float*)d_out;

  // Workspace layout (176 MB total):
  //   [0,16)    qb   bf16 [8192,1024]      } P1 f32 [8192,1024] aliases qb+kb
  //   [16,32)   kb   bf16 [8192,1024]      }   (dead after scores GEMM)
  //   [32,48)   vt   bf16 [1024,8192]  (V^T)
  //   [48,176)  S    bf16 [8192,8192]
  //   xb (16 MB) and Wb (6 MB) live INSIDE the S region (dead before S written)
  bf16_t* qb = (bf16_t*)d_ws;
  bf16_t* kb = qb + (size_t)N * D;
  bf16_t* vt = kb + (size_t)N * D;
  bf16_t* S = vt + (size_t)N * D;
  bf16_t* xb = S;                   // aliases start of S region (dead until S written)
  bf16_t* Wb = xb + (size_t)N * D;  // 3*D*D bf16 right after xb
  float* P1 = (float*)qb;           // 33.55 MB == qb+kb exactly

  // 1) fp32 -> bf16 converts (1/sqrt(D)=1/32 folded into Wq)
  cvt_f32_bf16<<<(N * D / 8) / 256, 256, 0, stream>>>(x, xb, N * D / 8, 1.0f);
  cvt_f32_bf16<<<(D * D / 8) / 256, 256, 0, stream>>>(Wq, Wb, D * D / 8, 0.03125f);
  cvt_f32_bf16<<<(D * D / 8) / 256, 256, 0, stream>>>(Wk, Wb + (size_t)D * D,
                                                      D * D / 8, 1.0f);
  cvt_f32_bf16<<<(D * D / 8) / 256, 256, 0, stream>>>(Wv, Wb + (size_t)2 * D * D,
                                                      D * D / 8, 1.0f);

  // 2) fused QKV (8-phase 256^2): [8192,1024] x [3072,1024]^T -> qb, kb, vt(V^T)
  gemm8p<2><<<(N / 256) * (3 * D / 256), 512, 0, stream>>>(
      xb, Wb, nullptr, nullptr, nullptr, qb, kb, vt, N, 3 * D, D, D, 1);

  // 3) scores (8-phase 256^2): qb @ kb^T -> S bf16 (scale folded into Wq)
  gemm8p<1><<<(N / 256) * (N / 256), 512, 0, stream>>>(
      qb, kb, S, nullptr, nullptr, nullptr, nullptr, nullptr, N, N, D, D, 1);

  // 4) row softmax in place on S
  softmax_rows<<<N, 256, 0, stream>>>(S, N);

  // 5) out = P @ V = S @ vt^T, split-K=2 (full-chip): ks=0 -> out, ks=1 -> P1
  gemm8p<0><<<(N / 256) * (D / 256) * 2, 512, 0, stream>>>(
      S, vt, nullptr, out, P1, nullptr, nullptr, nullptr, N, D, N / 2, N, 2);

  // 6) out += P1
  add_f32x4<<<(N * D / 4) / 256, 256, 0, stream>>>(out, P1);
}

// Round 4
// 373.244 us; speedup vs baseline: 1.2812x; 1.0932x over previous
//
#include <hip/hip_runtime.h>
#include <stdint.h>

typedef __bf16 bf16_t;
typedef __bf16 bf16x8 __attribute__((ext_vector_type(8)));
typedef float f32x4 __attribute__((ext_vector_type(4)));

typedef const __attribute__((address_space(1))) void gv_t;
typedef __attribute__((address_space(3))) void lv_t;

// ======================= 256x256 8-phase GEMM (T1+T2+T3+T4+T5) ====================
// BK=64, 8 waves (2Mx4N), per-wave 128x64 out split into 4 quadrants of 64x32.
// LDS: 2 bufs x {A0,A1,B0,B1} halves of [128 rows][64 k] bf16 (16 KB each) = 128 KB.
// Swizzle: byte ^= (row&7)<<4 on ds_read; inverse-swizzled global src for
// global_load_lds (linear LDS dest, rule #21).
// Supertile mapping: XCD x = bid&7 owns tm in [4x,4x+4); within XCD, tm is the
// fast index so ~32 concurrent blocks = 4tm x 8tn share panels in L2.
// Requires M == 8192 (ntM == 32) and grid % 8 == 0.

__device__ __forceinline__ void stage_half2(const bf16_t* g, int ldk, bf16_t* lh,
                                            int wave, int lane) {
#pragma unroll
  for (int i = 0; i < 2; ++i) {
    const int ub = i * 8192 + wave * 1024;       // wave-uniform LDS byte base
    const int o = ub + lane * 16;                // this lane's linear LDS byte
    const int row = o >> 7;                      // 128 B per row
    const int kb = (o & 127) ^ ((row & 7) << 4); // inverse swizzle on source
    const char* src = (const char*)g + (size_t)row * ((size_t)ldk * 2) + kb;
    __builtin_amdgcn_global_load_lds((gv_t*)src, (lv_t*)(lh + (ub >> 1)), 16, 0, 0);
  }
}

__device__ __forceinline__ bf16x8 ld_frag2(const bf16_t* h, int r, int s, int lane) {
  int byte = r * 128 + s * 64 + ((lane >> 4) << 4);
  byte ^= (r & 7) << 4;
  return *(const bf16x8*)((const char*)h + byte);
}

// EPI 0: PV — f32 out (ks0) / bf16 partial (ks1), both scaled by rvec[row].
// EPI 2: QKV epilogue (q,k row-major; v transposed).
// EPI 3: scores — store exp(acc) bf16 to Cb, per-block row sums to partial.
template <int EPI>
__global__ __launch_bounds__(512) void gemm8p(
    const bf16_t* __restrict__ A, const bf16_t* __restrict__ Bt,
    bf16_t* __restrict__ Cb, float* __restrict__ Cf0, bf16_t* __restrict__ Cf1b,
    const float* __restrict__ rvec, float* __restrict__ partial,
    bf16_t* __restrict__ qo, bf16_t* __restrict__ ko, bf16_t* __restrict__ vtb,
    int M, int N, int Kext, int ldk, int nks) {
  __shared__ __align__(16) bf16_t L[2][4][8192];  // [buf][A0,A1,B0,B1][128*64]

  const int tid = threadIdx.x;
  const int wave = tid >> 6;
  const int lane = tid & 63;

  // ---- supertile block mapping (XCD-aware) ----
  const int bid = blockIdx.x;
  const int x = bid & 7;
  const int j = bid >> 3;
  int tm, tn, ks;
  if (nks > 1) {  // PV: per XCD 4tm x 4tn x 2ks
    ks = j >> 4;
    tm = (x << 2) | (j & 3);
    tn = (j >> 2) & 3;
  } else {        // per XCD 4tm x ntN, tm fast
    ks = 0;
    tm = (x << 2) | (j & 3);
    tn = j >> 2;
  }

  const bf16_t* Ab = A + (size_t)tm * 256 * ldk + (size_t)ks * Kext;
  const bf16_t* Bb = Bt + (size_t)tn * 256 * ldk + (size_t)ks * Kext;

  const int wr64 = (wave >> 2) * 64;  // row base within each 128-row half
  const int wc32 = (wave & 3) * 32;   // col base within each 128-col half
  const int fr = lane & 15;
  const int nt = Kext >> 6;

  f32x4 acc00[4][2], acc01[4][2], acc10[4][2], acc11[4][2];
#pragma unroll
  for (int m = 0; m < 4; ++m)
#pragma unroll
    for (int n = 0; n < 2; ++n) {
      acc00[m][n] = (f32x4){0.f, 0.f, 0.f, 0.f};
      acc01[m][n] = (f32x4){0.f, 0.f, 0.f, 0.f};
      acc10[m][n] = (f32x4){0.f, 0.f, 0.f, 0.f};
      acc11[m][n] = (f32x4){0.f, 0.f, 0.f, 0.f};
    }

  // Prologue: tile0 fully + {A0,B1} of tile1 (12 loads); drain tile0, keep 4.
  stage_half2(Ab, ldk, &L[0][0][0], wave, lane);
  stage_half2(Ab + (size_t)128 * ldk, ldk, &L[0][1][0], wave, lane);
  stage_half2(Bb, ldk, &L[0][2][0], wave, lane);
  stage_half2(Bb + (size_t)128 * ldk, ldk, &L[0][3][0], wave, lane);
  stage_half2(Ab + 64, ldk, &L[1][0][0], wave, lane);
  stage_half2(Bb + (size_t)128 * ldk + 64, ldk, &L[1][3][0], wave, lane);
  asm volatile("s_waitcnt vmcnt(4)" ::: "memory");
  __builtin_amdgcn_s_barrier();

  bf16x8 a[4][2], bA[2][2], bB[2][2];

  for (int t = 0; t < nt; ++t) {
    const int cur = t & 1;
    const bf16_t* A0h = &L[cur][0][0];
    const bf16_t* A1h = &L[cur][1][0];
    const bf16_t* B0h = &L[cur][2][0];
    const bf16_t* B1h = &L[cur][3][0];

    // -- phase 1: quadrant (qm0,qn0); stage A1(t+1)
#pragma unroll
    for (int m = 0; m < 4; ++m)
#pragma unroll
      for (int s = 0; s < 2; ++s)
        a[m][s] = ld_frag2(A0h, wr64 + m * 16 + fr, s, lane);
#pragma unroll
    for (int n = 0; n < 2; ++n)
#pragma unroll
      for (int s = 0; s < 2; ++s)
        bA[n][s] = ld_frag2(B0h, wc32 + n * 16 + fr, s, lane);
    if (t + 1 < nt)
      stage_half2(Ab + (size_t)128 * ldk + (size_t)(t + 1) * 64, ldk,
                  &L[cur ^ 1][1][0], wave, lane);
    __builtin_amdgcn_s_barrier();
    __builtin_amdgcn_s_setprio(1);
#pragma unroll
    for (int s = 0; s < 2; ++s)
#pragma unroll
      for (int m = 0; m < 4; ++m)
#pragma unroll
        for (int n = 0; n < 2; ++n)
          acc00[m][n] = __builtin_amdgcn_mfma_f32_16x16x32_bf16(a[m][s], bA[n][s],
                                                                acc00[m][n], 0, 0, 0);
    __builtin_amdgcn_s_setprio(0);
    __builtin_amdgcn_s_barrier();

    // -- phase 2: quadrant (qm0,qn1); stage B0(t+1)
#pragma unroll
    for (int n = 0; n < 2; ++n)
#pragma unroll
      for (int s = 0; s < 2; ++s)
        bB[n][s] = ld_frag2(B1h, wc32 + n * 16 + fr, s, lane);
    if (t + 1 < nt)
      stage_half2(Bb + (size_t)(t + 1) * 64, ldk, &L[cur ^ 1][2][0], wave, lane);
    __builtin_amdgcn_s_barrier();
    __builtin_amdgcn_s_setprio(1);
#pragma unroll
    for (int s = 0; s < 2; ++s)
#pragma unroll
      for (int m = 0; m < 4; ++m)
#pragma unroll
        for (int n = 0; n < 2; ++n)
          acc01[m][n] = __builtin_amdgcn_mfma_f32_16x16x32_bf16(a[m][s], bB[n][s],
                                                                acc01[m][n], 0, 0, 0);
    __builtin_amdgcn_s_setprio(0);
    __builtin_amdgcn_s_barrier();

    // -- phase 3: quadrant (qm1,qn1); stage A0(t+2)
#pragma unroll
    for (int m = 0; m < 4; ++m)
#pragma unroll
      for (int s = 0; s < 2; ++s)
        a[m][s] = ld_frag2(A1h, wr64 + m * 16 + fr, s, lane);
    if (t + 2 < nt)
      stage_half2(Ab + (size_t)(t + 2) * 64, ldk, &L[cur][0][0], wave, lane);
    __builtin_amdgcn_s_barrier();
    __builtin_amdgcn_s_setprio(1);
#pragma unroll
    for (int s = 0; s < 2; ++s)
#pragma unroll
      for (int m = 0; m < 4; ++m)
#pragma unroll
        for (int n = 0; n < 2; ++n)
          acc11[m][n] = __builtin_amdgcn_mfma_f32_16x16x32_bf16(a[m][s], bB[n][s],
                                                                acc11[m][n], 0, 0, 0);
    __builtin_amdgcn_s_setprio(0);
    __builtin_amdgcn_s_barrier();

    // -- phase 4: quadrant (qm1,qn0); stage B1(t+2); boundary counted-vmcnt
    if (t + 2 < nt)
      stage_half2(Bb + (size_t)128 * ldk + (size_t)(t + 2) * 64, ldk, &L[cur][3][0],
                  wave, lane);
    __builtin_amdgcn_s_barrier();
    __builtin_amdgcn_s_setprio(1);
#pragma unroll
    for (int s = 0; s < 2; ++s)
#pragma unroll
      for (int m = 0; m < 4; ++m)
#pragma unroll
        for (int n = 0; n < 2; ++n)
          acc10[m][n] = __builtin_amdgcn_mfma_f32_16x16x32_bf16(a[m][s], bA[n][s],
                                                                acc10[m][n], 0, 0, 0);
    __builtin_amdgcn_s_setprio(0);
    // Drain everything of tile t+1; keep t+2's {A0,B1} (4 loads) in flight.
    if (t + 2 < nt)
      asm volatile("s_waitcnt vmcnt(4)" ::: "memory");
    else
      asm volatile("s_waitcnt vmcnt(0)" ::: "memory");
    __builtin_amdgcn_s_barrier();
  }

  // Epilogue. C/D mapping: col = lane&15, row = (lane>>4)*4 + j (m89-verified).
  const int fro = (lane >> 4) * 4;

  if (EPI == 3) {
    // exp all accs, store bf16 S (unnormalized weights)
#define EXPSTORE(ACC, QM, QN)                                                    \
  _Pragma("unroll") for (int m = 0; m < 4; ++m)                                  \
  _Pragma("unroll") for (int n = 0; n < 2; ++n)                                  \
  _Pragma("unroll") for (int jj = 0; jj < 4; ++jj) {                             \
    float e = __expf(ACC[m][n][jj]);                                             \
    ACC[m][n][jj] = e;                                                           \
    const int row = tm * 256 + QM * 128 + wr64 + m * 16 + fro + jj;              \
    const int col = tn * 256 + QN * 128 + wc32 + n * 16 + fr;                    \
    Cb[(size_t)row * N + col] = (bf16_t)e;                                       \
  }
    EXPSTORE(acc00, 0, 0)
    EXPSTORE(acc01, 0, 1)
    EXPSTORE(acc10, 1, 0)
    EXPSTORE(acc11, 1, 1)
#undef EXPSTORE
    // per-row partial sums: reduce over {QN, n} locally, then over fr lanes
    float* lsum = (float*)&L[0][0][0];  // L dead after K-loop; 4 KB reused
#define ROWSUM(A0, A1, QM)                                                       \
  _Pragma("unroll") for (int m = 0; m < 4; ++m) {                                \
    _Pragma("unroll") for (int jj = 0; jj < 4; ++jj) {                           \
      float s = A0[m][0][jj] + A0[m][1][jj] + A1[m][0][jj] + A1[m][1][jj];       \
      s += __shfl_xor(s, 1, 64);                                                 \
      s += __shfl_xor(s, 2, 64);                                                 \
      s += __shfl_xor(s, 4, 64);                                                 \
      s += __shfl_xor(s, 8, 64);                                                 \
      if (fr == 0) {                                                             \
        const int rl = QM * 128 + wr64 + m * 16 + fro + jj;                      \
        lsum[rl * 4 + (wave & 3)] = s;                                           \
      }                                                                          \
    }                                                                            \
  }
    ROWSUM(acc00, acc01, 0)
    ROWSUM(acc10, acc11, 1)
#undef ROWSUM
    __syncthreads();
    if (tid < 256) {
      float s = lsum[tid * 4] + lsum[tid * 4 + 1] + lsum[tid * 4 + 2] +
                lsum[tid * 4 + 3];
      partial[(size_t)tn * 8192 + tm * 256 + tid] = s;
    }
  } else if (EPI == 0) {
    // PV: scale by rvec[row]; ks0 -> f32 out, ks1 -> bf16 partial
#define PVSTORE(ACC, QM, QN)                                                     \
  _Pragma("unroll") for (int m = 0; m < 4; ++m) {                                \
    const int row = tm * 256 + QM * 128 + wr64 + m * 16 + fro;                   \
    const float4 rv = *(const float4*)&rvec[row];                                \
    _Pragma("unroll") for (int n = 0; n < 2; ++n) {                              \
      const int col = tn * 256 + QN * 128 + wc32 + n * 16 + fr;                  \
      if (ks == 0) {                                                             \
        _Pragma("unroll") for (int jj = 0; jj < 4; ++jj)                         \
            Cf0[(size_t)(row + jj) * N + col] =                                  \
                ACC[m][n][jj] * ((const float*)&rv)[jj];                         \
      } else {                                                                   \
        _Pragma("unroll") for (int jj = 0; jj < 4; ++jj)                         \
            Cf1b[(size_t)(row + jj) * N + col] =                                 \
                (bf16_t)(ACC[m][n][jj] * ((const float*)&rv)[jj]);               \
      }                                                                          \
    }                                                                            \
  }
    PVSTORE(acc00, 0, 0)
    PVSTORE(acc01, 0, 1)
    PVSTORE(acc10, 1, 0)
    PVSTORE(acc11, 1, 1)
#undef PVSTORE
  } else {
    // QKV: N==3072. 128-col tiles never straddle the 1024/2048 boundaries.
#define QKVSTORE(ACC, QM, QN)                                                    \
  _Pragma("unroll") for (int m = 0; m < 4; ++m) {                                \
    _Pragma("unroll") for (int n = 0; n < 2; ++n) {                              \
      const int row = tm * 256 + QM * 128 + wr64 + m * 16 + fro;                 \
      const int col = tn * 256 + QN * 128 + wc32 + n * 16 + fr;                  \
      if (col < 1024) {                                                          \
        _Pragma("unroll") for (int jj = 0; jj < 4; ++jj)                         \
            qo[(size_t)(row + jj) * 1024 + col] = (bf16_t)ACC[m][n][jj];         \
      } else if (col < 2048) {                                                   \
        _Pragma("unroll") for (int jj = 0; jj < 4; ++jj)                         \
            ko[(size_t)(row + jj) * 1024 + (col - 1024)] = (bf16_t)ACC[m][n][jj];\
      } else {                                                                   \
        union { bf16_t h[4]; uint2 u; } tpk;                                     \
        _Pragma("unroll") for (int jj = 0; jj < 4; ++jj)                         \
            tpk.h[jj] = (bf16_t)ACC[m][n][jj];                                   \
        *(uint2*)&vtb[(size_t)(col - 2048) * M + row] = tpk.u;                   \
      }                                                                          \
    }                                                                            \
  }
    QKVSTORE(acc00, 0, 0)
    QKVSTORE(acc01, 0, 1)
    QKVSTORE(acc10, 1, 0)
    QKVSTORE(acc11, 1, 1)
#undef QKVSTORE
  }
}

// ======================= converts, rowsum, add =======================
__global__ __launch_bounds__(256) void cvt_f32_bf16(const float* __restrict__ s,
                                                    bf16_t* __restrict__ d,
                                                    int n8, float scale) {
  int i = blockIdx.x * 256 + threadIdx.x;
  if (i >= n8) return;
  const float4* sp = (const float4*)s + (size_t)i * 2;
  float4 x0 = sp[0], x1 = sp[1];
  bf16x8 o;
  o[0] = (bf16_t)(x0.x * scale);
  o[1] = (bf16_t)(x0.y * scale);
  o[2] = (bf16_t)(x0.z * scale);
  o[3] = (bf16_t)(x0.w * scale);
  o[4] = (bf16_t)(x1.x * scale);
  o[5] = (bf16_t)(x1.y * scale);
  o[6] = (bf16_t)(x1.z * scale);
  o[7] = (bf16_t)(x1.w * scale);
  ((bf16x8*)d)[i] = o;
}

// r[row] = 1 / sum_tn partial[tn][row]
__global__ __launch_bounds__(256) void rowsum_recip(const float* __restrict__ partial,
                                                    float* __restrict__ r) {
  int row = blockIdx.x * 256 + threadIdx.x;
  float s = 0.f;
#pragma unroll
  for (int t = 0; t < 32; ++t) s += partial[(size_t)t * 8192 + row];
  r[row] = 1.0f / s;
}

// out[i] += float(p1b[i]), 8 elements per thread
__global__ __launch_bounds__(256) void add_p1(float* __restrict__ out,
                                              const bf16_t* __restrict__ p1b) {
  size_t i = (size_t)blockIdx.x * 256 + threadIdx.x;
  bf16x8 b = ((const bf16x8*)p1b)[i];
  float4 a0 = ((const float4*)out)[i * 2];
  float4 a1 = ((const float4*)out)[i * 2 + 1];
  a0.x += (float)b[0];
  a0.y += (float)b[1];
  a0.z += (float)b[2];
  a0.w += (float)b[3];
  a1.x += (float)b[4];
  a1.y += (float)b[5];
  a1.z += (float)b[6];
  a1.w += (float)b[7];
  ((float4*)out)[i * 2] = a0;
  ((float4*)out)[i * 2 + 1] = a1;
}

extern "C" void kernel_launch(void* const* d_in, const int* in_sizes, int n_in,
                              void* d_out, int out_size, void* d_ws, size_t ws_size,
                              hipStream_t stream) {
  const int N = 8192, D = 1024;
  const float* x = (const float*)d_in[0];
  const float* Wq = (const float*)d_in[1];
  const float* Wk = (const float*)d_in[2];
  const float* Wv = (const float*)d_in[3];
  float* out = (float*)d_out;

  // Workspace layout (176 MB total):
  //   [0,16)    qb   bf16 [8192,1024]   } after scores: P1b bf16 (qb region),
  //   [16,32)   kb   bf16 [8192,1024]   }   rvec f32 [8192] (kb region)
  //   [32,48)   vt   bf16 [1024,8192]  (V^T)
  //   [48,176)  S    bf16 [8192,8192]  (exp'd, unnormalized)
  //   xb (16 MB) and Wb (6 MB) live INSIDE the S region (dead before S written)
  //   partial f32 [32][8192] = 1 MB lives in d_out (dead until PV writes it)
  bf16_t* qb = (bf16_t*)d_ws;
  bf16_t* kb = qb + (size_t)N * D;
  bf16_t* vt = kb + (size_t)N * D;
  bf16_t* S = vt + (size_t)N * D;
  bf16_t* xb = S;                   // aliases start of S region (dead until S written)
  bf16_t* Wb = xb + (size_t)N * D;  // 3*D*D bf16 right after xb
  bf16_t* P1b = qb;                 // bf16 [8192,1024] (qb dead after scores)
  float* rvec = (float*)kb;         // f32 [8192]       (kb dead after scores)
  float* partial = out;             // f32 [32][8192] in d_out (dead until PV)

  // 1) fp32 -> bf16 converts (1/sqrt(D)=1/32 folded into Wq)
  cvt_f32_bf16<<<(N * D / 8) / 256, 256, 0, stream>>>(x, xb, N * D / 8, 1.0f);
  cvt_f32_bf16<<<(D * D / 8) / 256, 256, 0, stream>>>(Wq, Wb, D * D / 8, 0.03125f);
  cvt_f32_bf16<<<(D * D / 8) / 256, 256, 0, stream>>>(Wk, Wb + (size_t)D * D,
                                                      D * D / 8, 1.0f);
  cvt_f32_bf16<<<(D * D / 8) / 256, 256, 0, stream>>>(Wv, Wb + (size_t)2 * D * D,
                                                      D * D / 8, 1.0f);

  // 2) fused QKV (8-phase 256^2): [8192,1024] x [3072,1024]^T -> qb, kb, vt(V^T)
  gemm8p<2><<<(N / 256) * (3 * D / 256), 512, 0, stream>>>(
      xb, Wb, nullptr, nullptr, nullptr, nullptr, nullptr, qb, kb, vt,
      N, 3 * D, D, D, 1);

  // 3) scores: qb @ kb^T -> S = exp(logits) bf16 + row partial sums -> partial
  gemm8p<3><<<(N / 256) * (N / 256), 512, 0, stream>>>(
      qb, kb, S, nullptr, nullptr, nullptr, partial, nullptr, nullptr, nullptr,
      N, N, D, D, 1);

  // 4) r[row] = 1 / sum(partial)
  rowsum_recip<<<N / 256, 256, 0, stream>>>(partial, rvec);

  // 5) out = (S @ vt^T) * r, split-K=2: ks0 -> out f32, ks1 -> P1b bf16
  gemm8p<0><<<(N / 256) * (D / 256) * 2, 512, 0, stream>>>(
      S, vt, nullptr, out, P1b, rvec, nullptr, nullptr, nullptr, nullptr,
      N, D, N / 2, N, 2);

  // 6) out += P1b
  add_p1<<<(N * D / 8) / 256, 256, 0, stream>>>(out, P1b);
}

// Round 5
// 369.708 us; speedup vs baseline: 1.2934x; 1.0096x over previous
//
#include <hip/hip_runtime.h>
#include <stdint.h>

typedef __bf16 bf16_t;
typedef __bf16 bf16x8 __attribute__((ext_vector_type(8)));
typedef float f32x4 __attribute__((ext_vector_type(4)));

typedef const __attribute__((address_space(1))) void gv_t;
typedef __attribute__((address_space(3))) void lv_t;

// ======================= 256x256 8-phase GEMM (T1+T2+T3+T4+T5) ====================
// BK=64, 8 waves (2Mx4N), per-wave 128x64 out split into 4 quadrants of 64x32.
// LDS: 2 bufs x {A0,A1,B0,B1} halves of [128 rows][64 k] bf16 (16 KB each) = 128 KB.
// Swizzle: byte ^= (row&7)<<4 on ds_read; inverse-swizzled global src for
// global_load_lds (linear LDS dest, rule #21).
// Supertile mapping: XCD x = bid&7 owns tm in [4x,4x+4); tm is the fast index so
// ~32 concurrent blocks = 4tm x 8tn share panels in L2. Requires M == 8192.
// All shapes/strides are compile-time template params (strength-reduced addressing).

template <int LDK>
__device__ __forceinline__ void stage_half2(const bf16_t* g, bf16_t* lh,
                                            int wave, int lane) {
#pragma unroll
  for (int i = 0; i < 2; ++i) {
    const int ub = i * 8192 + wave * 1024;       // wave-uniform LDS byte base
    const int o = ub + lane * 16;                // this lane's linear LDS byte
    const int row = o >> 7;                      // 128 B per row
    const int kb = (o & 127) ^ ((row & 7) << 4); // inverse swizzle on source
    const char* src = (const char*)g + (size_t)row * (LDK * 2) + kb;
    __builtin_amdgcn_global_load_lds((gv_t*)src, (lv_t*)(lh + (ub >> 1)), 16, 0, 0);
  }
}

__device__ __forceinline__ bf16x8 ld_frag2(const bf16_t* h, int r, int s, int lane) {
  int byte = r * 128 + s * 64 + ((lane >> 4) << 4);
  byte ^= (r & 7) << 4;
  return *(const bf16x8*)((const char*)h + byte);
}

// EPI 0: PV — f32 out (ks0) / bf16 partial (ks1), both scaled by rvec[row].
// EPI 2: QKV epilogue (q,k row-major; v transposed).
// EPI 3: scores — store exp(acc) bf16 to Cb, per-block row sums to partial.
template <int EPI, int MM, int NN, int KEXT, int LDK, int NKS>
__global__ __launch_bounds__(512) void gemm8p(
    const bf16_t* __restrict__ A, const bf16_t* __restrict__ Bt,
    bf16_t* __restrict__ Cb, float* __restrict__ Cf0, bf16_t* __restrict__ Cf1b,
    const float* __restrict__ rvec, float* __restrict__ partial,
    bf16_t* __restrict__ qo, bf16_t* __restrict__ ko, bf16_t* __restrict__ vtb) {
  __shared__ __align__(16) bf16_t L[2][4][8192];  // [buf][A0,A1,B0,B1][128*64]

  const int tid = threadIdx.x;
  const int wave = tid >> 6;
  const int lane = tid & 63;

  // ---- supertile block mapping (XCD-aware) ----
  const int bid = blockIdx.x;
  const int x = bid & 7;
  const int j = bid >> 3;
  int tm, tn, ks;
  if (NKS > 1) {  // PV: per XCD 4tm x 4tn x 2ks
    ks = j >> 4;
    tm = (x << 2) | (j & 3);
    tn = (j >> 2) & 3;
  } else {        // per XCD 4tm x ntN, tm fast
    ks = 0;
    tm = (x << 2) | (j & 3);
    tn = j >> 2;
  }

  const bf16_t* Ab = A + (size_t)tm * (256 * LDK) + (size_t)ks * KEXT;
  const bf16_t* Bb = Bt + (size_t)tn * (256 * LDK) + (size_t)ks * KEXT;

  const int wr64 = (wave >> 2) * 64;  // row base within each 128-row half
  const int wc32 = (wave & 3) * 32;   // col base within each 128-col half
  const int fr = lane & 15;
  constexpr int nt = KEXT >> 6;

  f32x4 acc00[4][2], acc01[4][2], acc10[4][2], acc11[4][2];
#pragma unroll
  for (int m = 0; m < 4; ++m)
#pragma unroll
    for (int n = 0; n < 2; ++n) {
      acc00[m][n] = (f32x4){0.f, 0.f, 0.f, 0.f};
      acc01[m][n] = (f32x4){0.f, 0.f, 0.f, 0.f};
      acc10[m][n] = (f32x4){0.f, 0.f, 0.f, 0.f};
      acc11[m][n] = (f32x4){0.f, 0.f, 0.f, 0.f};
    }

  // Prologue: tile0 fully + {A0,B1} of tile1 (12 loads); drain tile0, keep 4.
  stage_half2<LDK>(Ab, &L[0][0][0], wave, lane);
  stage_half2<LDK>(Ab + (size_t)128 * LDK, &L[0][1][0], wave, lane);
  stage_half2<LDK>(Bb, &L[0][2][0], wave, lane);
  stage_half2<LDK>(Bb + (size_t)128 * LDK, &L[0][3][0], wave, lane);
  stage_half2<LDK>(Ab + 64, &L[1][0][0], wave, lane);
  stage_half2<LDK>(Bb + (size_t)128 * LDK + 64, &L[1][3][0], wave, lane);
  asm volatile("s_waitcnt vmcnt(4)" ::: "memory");
  __builtin_amdgcn_s_barrier();

  bf16x8 a[4][2], bA[2][2], bB[2][2];

#pragma unroll 1
  for (int t = 0; t < nt; ++t) {
    const int cur = t & 1;
    const bf16_t* A0h = &L[cur][0][0];
    const bf16_t* A1h = &L[cur][1][0];
    const bf16_t* B0h = &L[cur][2][0];
    const bf16_t* B1h = &L[cur][3][0];

    // -- phase 1: quadrant (qm0,qn0); stage A1(t+1)
#pragma unroll
    for (int m = 0; m < 4; ++m)
#pragma unroll
      for (int s = 0; s < 2; ++s)
        a[m][s] = ld_frag2(A0h, wr64 + m * 16 + fr, s, lane);
#pragma unroll
    for (int n = 0; n < 2; ++n)
#pragma unroll
      for (int s = 0; s < 2; ++s)
        bA[n][s] = ld_frag2(B0h, wc32 + n * 16 + fr, s, lane);
    if (t + 1 < nt)
      stage_half2<LDK>(Ab + (size_t)128 * LDK + (t + 1) * 64, &L[cur ^ 1][1][0],
                       wave, lane);
    __builtin_amdgcn_s_barrier();
    __builtin_amdgcn_s_setprio(1);
#pragma unroll
    for (int s = 0; s < 2; ++s)
#pragma unroll
      for (int m = 0; m < 4; ++m)
#pragma unroll
        for (int n = 0; n < 2; ++n)
          acc00[m][n] = __builtin_amdgcn_mfma_f32_16x16x32_bf16(a[m][s], bA[n][s],
                                                                acc00[m][n], 0, 0, 0);
    __builtin_amdgcn_s_setprio(0);
    __builtin_amdgcn_s_barrier();

    // -- phase 2: quadrant (qm0,qn1); stage B0(t+1)
#pragma unroll
    for (int n = 0; n < 2; ++n)
#pragma unroll
      for (int s = 0; s < 2; ++s)
        bB[n][s] = ld_frag2(B1h, wc32 + n * 16 + fr, s, lane);
    if (t + 1 < nt)
      stage_half2<LDK>(Bb + (t + 1) * 64, &L[cur ^ 1][2][0], wave, lane);
    __builtin_amdgcn_s_barrier();
    __builtin_amdgcn_s_setprio(1);
#pragma unroll
    for (int s = 0; s < 2; ++s)
#pragma unroll
      for (int m = 0; m < 4; ++m)
#pragma unroll
        for (int n = 0; n < 2; ++n)
          acc01[m][n] = __builtin_amdgcn_mfma_f32_16x16x32_bf16(a[m][s], bB[n][s],
                                                                acc01[m][n], 0, 0, 0);
    __builtin_amdgcn_s_setprio(0);
    __builtin_amdgcn_s_barrier();

    // -- phase 3: quadrant (qm1,qn1); stage A0(t+2)
#pragma unroll
    for (int m = 0; m < 4; ++m)
#pragma unroll
      for (int s = 0; s < 2; ++s)
        a[m][s] = ld_frag2(A1h, wr64 + m * 16 + fr, s, lane);
    if (t + 2 < nt)
      stage_half2<LDK>(Ab + (t + 2) * 64, &L[cur][0][0], wave, lane);
    __builtin_amdgcn_s_barrier();
    __builtin_amdgcn_s_setprio(1);
#pragma unroll
    for (int s = 0; s < 2; ++s)
#pragma unroll
      for (int m = 0; m < 4; ++m)
#pragma unroll
        for (int n = 0; n < 2; ++n)
          acc11[m][n] = __builtin_amdgcn_mfma_f32_16x16x32_bf16(a[m][s], bB[n][s],
                                                                acc11[m][n], 0, 0, 0);
    __builtin_amdgcn_s_setprio(0);
    __builtin_amdgcn_s_barrier();

    // -- phase 4: quadrant (qm1,qn0); stage B1(t+2); boundary counted-vmcnt
    if (t + 2 < nt)
      stage_half2<LDK>(Bb + (size_t)128 * LDK + (t + 2) * 64, &L[cur][3][0],
                       wave, lane);
    __builtin_amdgcn_s_barrier();
    __builtin_amdgcn_s_setprio(1);
#pragma unroll
    for (int s = 0; s < 2; ++s)
#pragma unroll
      for (int m = 0; m < 4; ++m)
#pragma unroll
        for (int n = 0; n < 2; ++n)
          acc10[m][n] = __builtin_amdgcn_mfma_f32_16x16x32_bf16(a[m][s], bA[n][s],
                                                                acc10[m][n], 0, 0, 0);
    __builtin_amdgcn_s_setprio(0);
    // Drain everything of tile t+1; keep t+2's {A0,B1} (4 loads) in flight.
    if (t + 2 < nt)
      asm volatile("s_waitcnt vmcnt(4)" ::: "memory");
    else
      asm volatile("s_waitcnt vmcnt(0)" ::: "memory");
    __builtin_amdgcn_s_barrier();
  }

  // Epilogue. C/D mapping: col = lane&15, row = (lane>>4)*4 + j (m89-verified).
  const int fro = (lane >> 4) * 4;

  if (EPI == 3) {
    // exp all accs, store bf16 S (unnormalized weights)
#define EXPSTORE(ACC, QM, QN)                                                    \
  _Pragma("unroll") for (int m = 0; m < 4; ++m)                                  \
  _Pragma("unroll") for (int n = 0; n < 2; ++n)                                  \
  _Pragma("unroll") for (int jj = 0; jj < 4; ++jj) {                             \
    float e = __expf(ACC[m][n][jj]);                                             \
    ACC[m][n][jj] = e;                                                           \
    const int row = tm * 256 + QM * 128 + wr64 + m * 16 + fro + jj;              \
    const int col = tn * 256 + QN * 128 + wc32 + n * 16 + fr;                    \
    Cb[(size_t)row * NN + col] = (bf16_t)e;                                      \
  }
    EXPSTORE(acc00, 0, 0)
    EXPSTORE(acc01, 0, 1)
    EXPSTORE(acc10, 1, 0)
    EXPSTORE(acc11, 1, 1)
#undef EXPSTORE
    // per-row partial sums: reduce over {QN, n} locally, then over fr lanes
    float* lsum = (float*)&L[0][0][0];  // L dead after K-loop; 4 KB reused
#define ROWSUM(A0, A1, QM)                                                       \
  _Pragma("unroll") for (int m = 0; m < 4; ++m) {                                \
    _Pragma("unroll") for (int jj = 0; jj < 4; ++jj) {                           \
      float s = A0[m][0][jj] + A0[m][1][jj] + A1[m][0][jj] + A1[m][1][jj];       \
      s += __shfl_xor(s, 1, 64);                                                 \
      s += __shfl_xor(s, 2, 64);                                                 \
      s += __shfl_xor(s, 4, 64);                                                 \
      s += __shfl_xor(s, 8, 64);                                                 \
      if (fr == 0) {                                                             \
        const int rl = QM * 128 + wr64 + m * 16 + fro + jj;                      \
        lsum[rl * 4 + (wave & 3)] = s;                                           \
      }                                                                          \
    }                                                                            \
  }
    ROWSUM(acc00, acc01, 0)
    ROWSUM(acc10, acc11, 1)
#undef ROWSUM
    __syncthreads();
    if (tid < 256) {
      float s = lsum[tid * 4] + lsum[tid * 4 + 1] + lsum[tid * 4 + 2] +
                lsum[tid * 4 + 3];
      partial[(size_t)tn * 8192 + tm * 256 + tid] = s;
    }
  } else if (EPI == 0) {
    // PV: scale by rvec[row]; ks0 -> f32 out, ks1 -> bf16 partial
#define PVSTORE(ACC, QM, QN)                                                     \
  _Pragma("unroll") for (int m = 0; m < 4; ++m) {                                \
    const int row = tm * 256 + QM * 128 + wr64 + m * 16 + fro;                   \
    const float4 rv = *(const float4*)&rvec[row];                                \
    _Pragma("unroll") for (int n = 0; n < 2; ++n) {                              \
      const int col = tn * 256 + QN * 128 + wc32 + n * 16 + fr;                  \
      if (ks == 0) {                                                             \
        _Pragma("unroll") for (int jj = 0; jj < 4; ++jj)                         \
            Cf0[(size_t)(row + jj) * NN + col] =                                 \
                ACC[m][n][jj] * ((const float*)&rv)[jj];                         \
      } else {                                                                   \
        _Pragma("unroll") for (int jj = 0; jj < 4; ++jj)                         \
            Cf1b[(size_t)(row + jj) * NN + col] =                                \
                (bf16_t)(ACC[m][n][jj] * ((const float*)&rv)[jj]);               \
      }                                                                          \
    }                                                                            \
  }
    PVSTORE(acc00, 0, 0)
    PVSTORE(acc01, 0, 1)
    PVSTORE(acc10, 1, 0)
    PVSTORE(acc11, 1, 1)
#undef PVSTORE
  } else {
    // QKV: NN==3072. 128-col tiles never straddle the 1024/2048 boundaries.
#define QKVSTORE(ACC, QM, QN)                                                    \
  _Pragma("unroll") for (int m = 0; m < 4; ++m) {                                \
    _Pragma("unroll") for (int n = 0; n < 2; ++n) {                              \
      const int row = tm * 256 + QM * 128 + wr64 + m * 16 + fro;                 \
      const int col = tn * 256 + QN * 128 + wc32 + n * 16 + fr;                  \
      if (col < 1024) {                                                          \
        _Pragma("unroll") for (int jj = 0; jj < 4; ++jj)                         \
            qo[(size_t)(row + jj) * 1024 + col] = (bf16_t)ACC[m][n][jj];         \
      } else if (col < 2048) {                                                   \
        _Pragma("unroll") for (int jj = 0; jj < 4; ++jj)                         \
            ko[(size_t)(row + jj) * 1024 + (col - 1024)] = (bf16_t)ACC[m][n][jj];\
      } else {                                                                   \
        union { bf16_t h[4]; uint2 u; } tpk;                                     \
        _Pragma("unroll") for (int jj = 0; jj < 4; ++jj)                         \
            tpk.h[jj] = (bf16_t)ACC[m][n][jj];                                   \
        *(uint2*)&vtb[(size_t)(col - 2048) * MM + row] = tpk.u;                  \
      }                                                                          \
    }                                                                            \
  }
    QKVSTORE(acc00, 0, 0)
    QKVSTORE(acc01, 0, 1)
    QKVSTORE(acc10, 1, 0)
    QKVSTORE(acc11, 1, 1)
#undef QKVSTORE
  }
}

// ======================= converts, rowsum, add =======================
__global__ __launch_bounds__(256) void cvt_f32_bf16(const float* __restrict__ s,
                                                    bf16_t* __restrict__ d,
                                                    int n8, float scale) {
  int i = blockIdx.x * 256 + threadIdx.x;
  if (i >= n8) return;
  const float4* sp = (const float4*)s + (size_t)i * 2;
  float4 x0 = sp[0], x1 = sp[1];
  bf16x8 o;
  o[0] = (bf16_t)(x0.x * scale);
  o[1] = (bf16_t)(x0.y * scale);
  o[2] = (bf16_t)(x0.z * scale);
  o[3] = (bf16_t)(x0.w * scale);
  o[4] = (bf16_t)(x1.x * scale);
  o[5] = (bf16_t)(x1.y * scale);
  o[6] = (bf16_t)(x1.z * scale);
  o[7] = (bf16_t)(x1.w * scale);
  ((bf16x8*)d)[i] = o;
}

// r[row] = 1 / sum_tn partial[tn][row]
__global__ __launch_bounds__(256) void rowsum_recip(const float* __restrict__ partial,
                                                    float* __restrict__ r) {
  int row = blockIdx.x * 256 + threadIdx.x;
  float s = 0.f;
#pragma unroll
  for (int t = 0; t < 32; ++t) s += partial[(size_t)t * 8192 + row];
  r[row] = 1.0f / s;
}

// out[i] += float(p1b[i]), 8 elements per thread
__global__ __launch_bounds__(256) void add_p1(float* __restrict__ out,
                                              const bf16_t* __restrict__ p1b) {
  size_t i = (size_t)blockIdx.x * 256 + threadIdx.x;
  bf16x8 b = ((const bf16x8*)p1b)[i];
  float4 a0 = ((const float4*)out)[i * 2];
  float4 a1 = ((const float4*)out)[i * 2 + 1];
  a0.x += (float)b[0];
  a0.y += (float)b[1];
  a0.z += (float)b[2];
  a0.w += (float)b[3];
  a1.x += (float)b[4];
  a1.y += (float)b[5];
  a1.z += (float)b[6];
  a1.w += (float)b[7];
  ((float4*)out)[i * 2] = a0;
  ((float4*)out)[i * 2 + 1] = a1;
}

extern "C" void kernel_launch(void* const* d_in, const int* in_sizes, int n_in,
                              void* d_out, int out_size, void* d_ws, size_t ws_size,
                              hipStream_t stream) {
  const int N = 8192, D = 1024;
  const float* x = (const float*)d_in[0];
  const float* Wq = (const float*)d_in[1];
  const float* Wk = (const float*)d_in[2];
  const float* Wv = (const float*)d_in[3];
  float* out = (float*)d_out;

  // Workspace layout (176 MB total):
  //   [0,16)    qb   bf16 [8192,1024]   } after scores: P1b bf16 (qb region),
  //   [16,32)   kb   bf16 [8192,1024]   }   rvec f32 [8192] (kb region)
  //   [32,48)   vt   bf16 [1024,8192]  (V^T)
  //   [48,176)  S    bf16 [8192,8192]  (exp'd, unnormalized)
  //   xb (16 MB) and Wb (6 MB) live INSIDE the S region (dead before S written)
  //   partial f32 [32][8192] = 1 MB lives in d_out (dead until PV writes it)
  bf16_t* qb = (bf16_t*)d_ws;
  bf16_t* kb = qb + (size_t)N * D;
  bf16_t* vt = kb + (size_t)N * D;
  bf16_t* S = vt + (size_t)N * D;
  bf16_t* xb = S;                   // aliases start of S region (dead until S written)
  bf16_t* Wb = xb + (size_t)N * D;  // 3*D*D bf16 right after xb
  bf16_t* P1b = qb;                 // bf16 [8192,1024] (qb dead after scores)
  float* rvec = (float*)kb;         // f32 [8192]       (kb dead after scores)
  float* partial = out;             // f32 [32][8192] in d_out (dead until PV)

  // 1) fp32 -> bf16 converts (1/sqrt(D)=1/32 folded into Wq)
  cvt_f32_bf16<<<(N * D / 8) / 256, 256, 0, stream>>>(x, xb, N * D / 8, 1.0f);
  cvt_f32_bf16<<<(D * D / 8) / 256, 256, 0, stream>>>(Wq, Wb, D * D / 8, 0.03125f);
  cvt_f32_bf16<<<(D * D / 8) / 256, 256, 0, stream>>>(Wk, Wb + (size_t)D * D,
                                                      D * D / 8, 1.0f);
  cvt_f32_bf16<<<(D * D / 8) / 256, 256, 0, stream>>>(Wv, Wb + (size_t)2 * D * D,
                                                      D * D / 8, 1.0f);

  // 2) fused QKV (8-phase 256^2): [8192,1024] x [3072,1024]^T -> qb, kb, vt(V^T)
  gemm8p<2, 8192, 3072, 1024, 1024, 1><<<(N / 256) * (3 * D / 256), 512, 0, stream>>>(
      xb, Wb, nullptr, nullptr, nullptr, nullptr, nullptr, qb, kb, vt);

  // 3) scores: qb @ kb^T -> S = exp(logits) bf16 + row partial sums -> partial
  gemm8p<3, 8192, 8192, 1024, 1024, 1><<<(N / 256) * (N / 256), 512, 0, stream>>>(
      qb, kb, S, nullptr, nullptr, nullptr, partial, nullptr, nullptr, nullptr);

  // 4) r[row] = 1 / sum(partial)
  rowsum_recip<<<N / 256, 256, 0, stream>>>(partial, rvec);

  // 5) out = (S @ vt^T) * r, split-K=2: ks0 -> out f32, ks1 -> P1b bf16
  gemm8p<0, 8192, 1024, 4096, 8192, 2><<<(N / 256) * (D / 256) * 2, 512, 0, stream>>>(
      S, vt, nullptr, out, P1b, rvec, nullptr, nullptr, nullptr, nullptr);

  // 6) out += P1b
  add_p1<<<(N * D / 8) / 256, 256, 0, stream>>>(out, P1b);
}

// Round 6
// 330.359 us; speedup vs baseline: 1.4475x; 1.1191x over previous
//
#include <hip/hip_runtime.h>
#include <stdint.h>

typedef __bf16 bf16_t;
typedef __bf16 bf16x8 __attribute__((ext_vector_type(8)));
typedef float f32x4 __attribute__((ext_vector_type(4)));
typedef int i32x4 __attribute__((ext_vector_type(4)));
typedef int i32x8 __attribute__((ext_vector_type(8)));

typedef const __attribute__((address_space(1))) void gv_t;
typedef __attribute__((address_space(3))) void lv_t;

// ======================= 256x256 8-phase bf16 GEMM (QKV + PV) ====================
// Proven template (rounds 2-5). BK=64, 8 waves, XCD supertile mapping.

template <int LDK>
__device__ __forceinline__ void stage_half2(const bf16_t* g, bf16_t* lh,
                                            int wave, int lane) {
#pragma unroll
  for (int i = 0; i < 2; ++i) {
    const int ub = i * 8192 + wave * 1024;
    const int o = ub + lane * 16;
    const int row = o >> 7;
    const int kb = (o & 127) ^ ((row & 7) << 4);
    const char* src = (const char*)g + (size_t)row * (LDK * 2) + kb;
    __builtin_amdgcn_global_load_lds((gv_t*)src, (lv_t*)(lh + (ub >> 1)), 16, 0, 0);
  }
}

__device__ __forceinline__ bf16x8 ld_frag2(const bf16_t* h, int r, int s, int lane) {
  int byte = r * 128 + s * 64 + ((lane >> 4) << 4);
  byte ^= (r & 7) << 4;
  return *(const bf16x8*)((const char*)h + byte);
}

// EPI 0: PV — f32 out (ks0) / bf16 partial (ks1), scaled by rvec[row].
// EPI 2: QKV — q,k stored as fp8 e4m3 (1 B); v transposed bf16.
template <int EPI, int MM, int NN, int KEXT, int LDK, int NKS>
__global__ __launch_bounds__(512) void gemm8p(
    const bf16_t* __restrict__ A, const bf16_t* __restrict__ Bt,
    float* __restrict__ Cf0, bf16_t* __restrict__ Cf1b,
    const float* __restrict__ rvec,
    uint8_t* __restrict__ qo, uint8_t* __restrict__ ko,
    bf16_t* __restrict__ vtb) {
  __shared__ __align__(16) bf16_t L[2][4][8192];

  const int tid = threadIdx.x;
  const int wave = tid >> 6;
  const int lane = tid & 63;

  const int bid = blockIdx.x;
  const int x = bid & 7;
  const int j = bid >> 3;
  int tm, tn, ks;
  if (NKS > 1) {  // PV: per XCD 4tm x 4tn x 2ks
    ks = j >> 4;
    tm = (x << 2) | (j & 3);
    tn = (j >> 2) & 3;
  } else {        // per XCD 4tm x ntN, tm fast
    ks = 0;
    tm = (x << 2) | (j & 3);
    tn = j >> 2;
  }

  const bf16_t* Ab = A + (size_t)tm * (256 * LDK) + (size_t)ks * KEXT;
  const bf16_t* Bb = Bt + (size_t)tn * (256 * LDK) + (size_t)ks * KEXT;

  const int wr64 = (wave >> 2) * 64;
  const int wc32 = (wave & 3) * 32;
  const int fr = lane & 15;
  constexpr int nt = KEXT >> 6;

  f32x4 acc00[4][2], acc01[4][2], acc10[4][2], acc11[4][2];
#pragma unroll
  for (int m = 0; m < 4; ++m)
#pragma unroll
    for (int n = 0; n < 2; ++n) {
      acc00[m][n] = (f32x4){0.f, 0.f, 0.f, 0.f};
      acc01[m][n] = (f32x4){0.f, 0.f, 0.f, 0.f};
      acc10[m][n] = (f32x4){0.f, 0.f, 0.f, 0.f};
      acc11[m][n] = (f32x4){0.f, 0.f, 0.f, 0.f};
    }

  stage_half2<LDK>(Ab, &L[0][0][0], wave, lane);
  stage_half2<LDK>(Ab + (size_t)128 * LDK, &L[0][1][0], wave, lane);
  stage_half2<LDK>(Bb, &L[0][2][0], wave, lane);
  stage_half2<LDK>(Bb + (size_t)128 * LDK, &L[0][3][0], wave, lane);
  stage_half2<LDK>(Ab + 64, &L[1][0][0], wave, lane);
  stage_half2<LDK>(Bb + (size_t)128 * LDK + 64, &L[1][3][0], wave, lane);
  asm volatile("s_waitcnt vmcnt(4)" ::: "memory");
  __builtin_amdgcn_s_barrier();

  bf16x8 a[4][2], bA[2][2], bB[2][2];

#pragma unroll 1
  for (int t = 0; t < nt; ++t) {
    const int cur = t & 1;
    const bf16_t* A0h = &L[cur][0][0];
    const bf16_t* A1h = &L[cur][1][0];
    const bf16_t* B0h = &L[cur][2][0];
    const bf16_t* B1h = &L[cur][3][0];

#pragma unroll
    for (int m = 0; m < 4; ++m)
#pragma unroll
      for (int s = 0; s < 2; ++s)
        a[m][s] = ld_frag2(A0h, wr64 + m * 16 + fr, s, lane);
#pragma unroll
    for (int n = 0; n < 2; ++n)
#pragma unroll
      for (int s = 0; s < 2; ++s)
        bA[n][s] = ld_frag2(B0h, wc32 + n * 16 + fr, s, lane);
    if (t + 1 < nt)
      stage_half2<LDK>(Ab + (size_t)128 * LDK + (t + 1) * 64, &L[cur ^ 1][1][0],
                       wave, lane);
    __builtin_amdgcn_s_barrier();
    __builtin_amdgcn_s_setprio(1);
#pragma unroll
    for (int s = 0; s < 2; ++s)
#pragma unroll
      for (int m = 0; m < 4; ++m)
#pragma unroll
        for (int n = 0; n < 2; ++n)
          acc00[m][n] = __builtin_amdgcn_mfma_f32_16x16x32_bf16(a[m][s], bA[n][s],
                                                                acc00[m][n], 0, 0, 0);
    __builtin_amdgcn_s_setprio(0);
    __builtin_amdgcn_s_barrier();

#pragma unroll
    for (int n = 0; n < 2; ++n)
#pragma unroll
      for (int s = 0; s < 2; ++s)
        bB[n][s] = ld_frag2(B1h, wc32 + n * 16 + fr, s, lane);
    if (t + 1 < nt)
      stage_half2<LDK>(Bb + (t + 1) * 64, &L[cur ^ 1][2][0], wave, lane);
    __builtin_amdgcn_s_barrier();
    __builtin_amdgcn_s_setprio(1);
#pragma unroll
    for (int s = 0; s < 2; ++s)
#pragma unroll
      for (int m = 0; m < 4; ++m)
#pragma unroll
        for (int n = 0; n < 2; ++n)
          acc01[m][n] = __builtin_amdgcn_mfma_f32_16x16x32_bf16(a[m][s], bB[n][s],
                                                                acc01[m][n], 0, 0, 0);
    __builtin_amdgcn_s_setprio(0);
    __builtin_amdgcn_s_barrier();

#pragma unroll
    for (int m = 0; m < 4; ++m)
#pragma unroll
      for (int s = 0; s < 2; ++s)
        a[m][s] = ld_frag2(A1h, wr64 + m * 16 + fr, s, lane);
    if (t + 2 < nt)
      stage_half2<LDK>(Ab + (t + 2) * 64, &L[cur][0][0], wave, lane);
    __builtin_amdgcn_s_barrier();
    __builtin_amdgcn_s_setprio(1);
#pragma unroll
    for (int s = 0; s < 2; ++s)
#pragma unroll
      for (int m = 0; m < 4; ++m)
#pragma unroll
        for (int n = 0; n < 2; ++n)
          acc11[m][n] = __builtin_amdgcn_mfma_f32_16x16x32_bf16(a[m][s], bB[n][s],
                                                                acc11[m][n], 0, 0, 0);
    __builtin_amdgcn_s_setprio(0);
    __builtin_amdgcn_s_barrier();

    if (t + 2 < nt)
      stage_half2<LDK>(Bb + (size_t)128 * LDK + (t + 2) * 64, &L[cur][3][0],
                       wave, lane);
    __builtin_amdgcn_s_barrier();
    __builtin_amdgcn_s_setprio(1);
#pragma unroll
    for (int s = 0; s < 2; ++s)
#pragma unroll
      for (int m = 0; m < 4; ++m)
#pragma unroll
        for (int n = 0; n < 2; ++n)
          acc10[m][n] = __builtin_amdgcn_mfma_f32_16x16x32_bf16(a[m][s], bA[n][s],
                                                                acc10[m][n], 0, 0, 0);
    __builtin_amdgcn_s_setprio(0);
    if (t + 2 < nt)
      asm volatile("s_waitcnt vmcnt(4)" ::: "memory");
    else
      asm volatile("s_waitcnt vmcnt(0)" ::: "memory");
    __builtin_amdgcn_s_barrier();
  }

  const int fro = (lane >> 4) * 4;
#define STORE_QUAD(ACC, QM, QN)                                                  \
  _Pragma("unroll") for (int m = 0; m < 4; ++m) {                                \
    _Pragma("unroll") for (int n = 0; n < 2; ++n) {                              \
      const int row = tm * 256 + QM * 128 + wr64 + m * 16 + fro;                 \
      const int col = tn * 256 + QN * 128 + wc32 + n * 16 + fr;                  \
      if (EPI == 0) {                                                            \
        const float4 rv = *(const float4*)&rvec[row];                            \
        if (ks == 0) {                                                           \
          _Pragma("unroll") for (int jj = 0; jj < 4; ++jj)                       \
              Cf0[(size_t)(row + jj) * NN + col] =                               \
                  ACC[m][n][jj] * ((const float*)&rv)[jj];                       \
        } else {                                                                 \
          _Pragma("unroll") for (int jj = 0; jj < 4; ++jj)                       \
              Cf1b[(size_t)(row + jj) * NN + col] =                              \
                  (bf16_t)(ACC[m][n][jj] * ((const float*)&rv)[jj]);             \
        }                                                                        \
      } else {                                                                   \
        if (col < 1024) {                                                        \
          _Pragma("unroll") for (int jj = 0; jj < 4; ++jj) {                     \
            int pk = __builtin_amdgcn_cvt_pk_fp8_f32(ACC[m][n][jj],              \
                                                     ACC[m][n][jj], 0, false);   \
            qo[(size_t)(row + jj) * 1024 + col] = (uint8_t)pk;                   \
          }                                                                      \
        } else if (col < 2048) {                                                 \
          _Pragma("unroll") for (int jj = 0; jj < 4; ++jj) {                     \
            int pk = __builtin_amdgcn_cvt_pk_fp8_f32(ACC[m][n][jj],              \
                                                     ACC[m][n][jj], 0, false);   \
            ko[(size_t)(row + jj) * 1024 + (col - 1024)] = (uint8_t)pk;          \
          }                                                                      \
        } else {                                                                 \
          union { bf16_t h[4]; uint2 u; } tpk;                                   \
          _Pragma("unroll") for (int jj = 0; jj < 4; ++jj)                       \
              tpk.h[jj] = (bf16_t)ACC[m][n][jj];                                 \
          *(uint2*)&vtb[(size_t)(col - 2048) * MM + row] = tpk.u;                \
        }                                                                        \
      }                                                                          \
    }                                                                            \
  }
  STORE_QUAD(acc00, 0, 0)
  STORE_QUAD(acc01, 0, 1)
  STORE_QUAD(acc10, 1, 0)
  STORE_QUAD(acc11, 1, 1)
#undef STORE_QUAD
}

// ======================= MX-fp8 scores GEMM (m97 structure, 128^2, BK=128) =======
// S[row][col] = exp(q[row]·k[col]); q,k fp8 e4m3, unit e8m0 scales (0x7F).
// LDS 64 KB -> 2 blocks/CU. Frag: row=lane&15, k-bytes=(lane>>4)*32..+31.
// Swizzle byte ^= (row&7)<<4 on read; inverse-swizzled global source.

__device__ __forceinline__ void stage_fp8(const uint8_t* g, uint8_t* l,
                                          int wave, int lane) {
#pragma unroll
  for (int i = 0; i < 4; ++i) {
    const int ub = i * 4096 + wave * 1024;
    const int o = ub + lane * 16;
    const int row = o >> 7;
    const int col = (o & 127) ^ ((row & 7) << 4);
    __builtin_amdgcn_global_load_lds((gv_t*)(g + (size_t)row * 1024 + col),
                                     (lv_t*)(l + ub), 16, 0, 0);
  }
}

__device__ __forceinline__ i32x8 ld_frag8(const uint8_t* base128, int row, int kg) {
  const int sw = (row & 7) << 4;
  const uint8_t* b = base128 + row * 128;
  i32x4 lo = *(const i32x4*)(b + (kg ^ sw));
  i32x4 hi = *(const i32x4*)(b + ((kg | 16) ^ sw));
  i32x8 v;
  v[0] = lo[0]; v[1] = lo[1]; v[2] = lo[2]; v[3] = lo[3];
  v[4] = hi[0]; v[5] = hi[1]; v[6] = hi[2]; v[7] = hi[3];
  return v;
}

__global__ __launch_bounds__(256) void scores_fp8(
    const uint8_t* __restrict__ qf, const uint8_t* __restrict__ kf,
    bf16_t* __restrict__ S, float* __restrict__ partial) {
  __shared__ __align__(16) uint8_t lA[2][128 * 128];
  __shared__ __align__(16) uint8_t lB[2][128 * 128];

  const int tid = threadIdx.x;
  const int wave = tid >> 6;
  const int lane = tid & 63;

  // supertile: per XCD 8tm x 8tn concurrent (2 blocks/CU) -> 2 MB L2 set
  const int bid = blockIdx.x;
  const int x = bid & 7;
  const int j = bid >> 3;
  const int tm = (x << 3) | (j & 7);  // 0..63
  const int tn = j >> 3;              // 0..63

  const uint8_t* Ab = qf + (size_t)tm * 128 * 1024;
  const uint8_t* Bb = kf + (size_t)tn * 128 * 1024;

  const int wr = (wave >> 1) * 64;
  const int wc = (wave & 1) * 64;
  const int fr = lane & 15;
  const int kg = (lane >> 4) * 32;

  f32x4 acc[4][4];
#pragma unroll
  for (int m = 0; m < 4; ++m)
#pragma unroll
    for (int n = 0; n < 4; ++n) acc[m][n] = (f32x4){0.f, 0.f, 0.f, 0.f};

  stage_fp8(Ab, lA[0], wave, lane);
  stage_fp8(Bb, lB[0], wave, lane);
  __syncthreads();

#pragma unroll 1
  for (int kt = 0; kt < 8; ++kt) {
    const int cur = kt & 1;
    if (kt < 7) {
      stage_fp8(Ab + (kt + 1) * 128, lA[cur ^ 1], wave, lane);
      stage_fp8(Bb + (kt + 1) * 128, lB[cur ^ 1], wave, lane);
    }
    i32x8 a[4], b[4];
#pragma unroll
    for (int m = 0; m < 4; ++m) a[m] = ld_frag8(lA[cur], wr + m * 16 + fr, kg);
#pragma unroll
    for (int n = 0; n < 4; ++n) b[n] = ld_frag8(lB[cur], wc + n * 16 + fr, kg);
#pragma unroll
    for (int m = 0; m < 4; ++m)
#pragma unroll
      for (int n = 0; n < 4; ++n)
        acc[m][n] = __builtin_amdgcn_mfma_scale_f32_16x16x128_f8f6f4(
            a[m], b[n], acc[m][n], 0, 0, 0, 0x7F7F7F7F, 0, 0x7F7F7F7F);
    __syncthreads();
  }

  // Epilogue: exp, bf16 store, per-row partial sums.
  const int fro = (lane >> 4) * 4;
  float* lsum = (float*)&lA[0][0];
#pragma unroll
  for (int m = 0; m < 4; ++m) {
#pragma unroll
    for (int jj = 0; jj < 4; ++jj) {
      const int rl = wr + m * 16 + fro + jj;
      float s = 0.f;
#pragma unroll
      for (int n = 0; n < 4; ++n) {
        float e = __expf(acc[m][n][jj]);
        const int col = tn * 128 + wc + n * 16 + fr;
        S[(size_t)(tm * 128 + rl) * 8192 + col] = (bf16_t)e;
        s += e;
      }
      s += __shfl_xor(s, 1, 64);
      s += __shfl_xor(s, 2, 64);
      s += __shfl_xor(s, 4, 64);
      s += __shfl_xor(s, 8, 64);
      if (fr == 0) lsum[rl * 2 + (wave & 1)] = s;
    }
  }
  __syncthreads();
  if (tid < 128)
    partial[(size_t)tn * 8192 + tm * 128 + tid] = lsum[tid * 2] + lsum[tid * 2 + 1];
}

// ======================= converts, rowsum, add =======================
__global__ __launch_bounds__(256) void cvt_f32_bf16(const float* __restrict__ s,
                                                    bf16_t* __restrict__ d,
                                                    int n8, float scale) {
  int i = blockIdx.x * 256 + threadIdx.x;
  if (i >= n8) return;
  const float4* sp = (const float4*)s + (size_t)i * 2;
  float4 x0 = sp[0], x1 = sp[1];
  bf16x8 o;
  o[0] = (bf16_t)(x0.x * scale);
  o[1] = (bf16_t)(x0.y * scale);
  o[2] = (bf16_t)(x0.z * scale);
  o[3] = (bf16_t)(x0.w * scale);
  o[4] = (bf16_t)(x1.x * scale);
  o[5] = (bf16_t)(x1.y * scale);
  o[6] = (bf16_t)(x1.z * scale);
  o[7] = (bf16_t)(x1.w * scale);
  ((bf16x8*)d)[i] = o;
}

// r[row] = 1 / sum_tn partial[tn][row], tn = 0..63
__global__ __launch_bounds__(256) void rowsum_recip(const float* __restrict__ partial,
                                                    float* __restrict__ r) {
  int row = blockIdx.x * 256 + threadIdx.x;
  float s = 0.f;
#pragma unroll
  for (int t = 0; t < 64; ++t) s += partial[(size_t)t * 8192 + row];
  r[row] = 1.0f / s;
}

__global__ __launch_bounds__(256) void add_p1(float* __restrict__ out,
                                              const bf16_t* __restrict__ p1b) {
  size_t i = (size_t)blockIdx.x * 256 + threadIdx.x;
  bf16x8 b = ((const bf16x8*)p1b)[i];
  float4 a0 = ((const float4*)out)[i * 2];
  float4 a1 = ((const float4*)out)[i * 2 + 1];
  a0.x += (float)b[0];
  a0.y += (float)b[1];
  a0.z += (float)b[2];
  a0.w += (float)b[3];
  a1.x += (float)b[4];
  a1.y += (float)b[5];
  a1.z += (float)b[6];
  a1.w += (float)b[7];
  ((float4*)out)[i * 2] = a0;
  ((float4*)out)[i * 2 + 1] = a1;
}

extern "C" void kernel_launch(void* const* d_in, const int* in_sizes, int n_in,
                              void* d_out, int out_size, void* d_ws, size_t ws_size,
                              hipStream_t stream) {
  const int N = 8192, D = 1024;
  const float* x = (const float*)d_in[0];
  const float* Wq = (const float*)d_in[1];
  const float* Wk = (const float*)d_in[2];
  const float* Wv = (const float*)d_in[3];
  float* out = (float*)d_out;

  // Workspace layout:
  //   [0,8)    qf  fp8 [8192,1024]   } after scores: P1b bf16 [8192,1024] (16 MB)
  //   [8,16)   kf  fp8 [8192,1024]   }
  //   [16,32)  vt  bf16 [1024,8192]  (V^T)
  //   [32,160) S   bf16 [8192,8192]  (exp'd, unnormalized)
  //   [160,160.03) rvec f32 [8192]
  //   xb (16 MB) + Wb (6 MB) alias the start of S (dead before S written)
  //   partial f32 [64][8192] = 2 MB lives in d_out (dead until PV)
  uint8_t* qf = (uint8_t*)d_ws;
  uint8_t* kf = qf + (size_t)N * D;
  bf16_t* vt = (bf16_t*)(kf + (size_t)N * D);
  bf16_t* S = vt + (size_t)N * D;
  bf16_t* xb = S;
  bf16_t* Wb = xb + (size_t)N * D;
  bf16_t* P1b = (bf16_t*)d_ws;
  float* rvec = (float*)(S + (size_t)N * N);
  float* partial = out;

  const float sq = 0.1767766953f;  // 1/sqrt(32); folded into both Wq and Wk

  // 1) fp32 -> bf16 converts
  cvt_f32_bf16<<<(N * D / 8) / 256, 256, 0, stream>>>(x, xb, N * D / 8, 1.0f);
  cvt_f32_bf16<<<(D * D / 8) / 256, 256, 0, stream>>>(Wq, Wb, D * D / 8, sq);
  cvt_f32_bf16<<<(D * D / 8) / 256, 256, 0, stream>>>(Wk, Wb + (size_t)D * D,
                                                      D * D / 8, sq);
  cvt_f32_bf16<<<(D * D / 8) / 256, 256, 0, stream>>>(Wv, Wb + (size_t)2 * D * D,
                                                      D * D / 8, 1.0f);

  // 2) fused QKV: q,k -> fp8 e4m3; v -> vt bf16 (V^T)
  gemm8p<2, 8192, 3072, 1024, 1024, 1><<<(N / 256) * (3 * D / 256), 512, 0, stream>>>(
      xb, Wb, nullptr, nullptr, nullptr, qf, kf, vt);

  // 3) scores (MX-fp8, K=128 scaled MFMA): S = exp(q·k) + partial row sums
  scores_fp8<<<(N / 128) * (N / 128), 256, 0, stream>>>(qf, kf, S, partial);

  // 4) r[row] = 1 / sum(partial)
  rowsum_recip<<<N / 256, 256, 0, stream>>>(partial, rvec);

  // 5) out = (S @ vt^T) * r, split-K=2: ks0 -> out f32, ks1 -> P1b bf16
  gemm8p<0, 8192, 1024, 4096, 8192, 2><<<(N / 256) * (D / 256) * 2, 512, 0, stream>>>(
      S, vt, out, P1b, rvec, nullptr, nullptr, nullptr);

  // 6) out += P1b
  add_p1<<<(N * D / 8) / 256, 256, 0, stream>>>(out, P1b);
}

// Round 7
// 314.284 us; speedup vs baseline: 1.5216x; 1.0511x over previous
//
#include <hip/hip_runtime.h>
#include <stdint.h>

typedef __bf16 bf16_t;
typedef __bf16 bf16x8 __attribute__((ext_vector_type(8)));
typedef float f32x4 __attribute__((ext_vector_type(4)));
typedef int i32x4 __attribute__((ext_vector_type(4)));
typedef int i32x8 __attribute__((ext_vector_type(8)));

typedef const __attribute__((address_space(1))) void gv_t;
typedef __attribute__((address_space(3))) void lv_t;

// ======================= 256x256 8-phase bf16 GEMM (QKV + PV) ====================
// Proven template (rounds 2-6). BK=64, 8 waves, XCD supertile mapping.

template <int LDK>
__device__ __forceinline__ void stage_half2(const bf16_t* g, bf16_t* lh,
                                            int wave, int lane) {
#pragma unroll
  for (int i = 0; i < 2; ++i) {
    const int ub = i * 8192 + wave * 1024;
    const int o = ub + lane * 16;
    const int row = o >> 7;
    const int kb = (o & 127) ^ ((row & 7) << 4);
    const char* src = (const char*)g + (size_t)row * (LDK * 2) + kb;
    __builtin_amdgcn_global_load_lds((gv_t*)src, (lv_t*)(lh + (ub >> 1)), 16, 0, 0);
  }
}

__device__ __forceinline__ bf16x8 ld_frag2(const bf16_t* h, int r, int s, int lane) {
  int byte = r * 128 + s * 64 + ((lane >> 4) << 4);
  byte ^= (r & 7) << 4;
  return *(const bf16x8*)((const char*)h + byte);
}

// EPI 0: PV — f32 out (ks0) / bf16 partial (ks1), scaled by rvec[row].
// EPI 2: QKV — q,k stored as fp8 e4m3 (1 B); v transposed bf16.
template <int EPI, int MM, int NN, int KEXT, int LDK, int NKS>
__global__ __launch_bounds__(512) void gemm8p(
    const bf16_t* __restrict__ A, const bf16_t* __restrict__ Bt,
    float* __restrict__ Cf0, bf16_t* __restrict__ Cf1b,
    const float* __restrict__ rvec,
    uint8_t* __restrict__ qo, uint8_t* __restrict__ ko,
    bf16_t* __restrict__ vtb) {
  __shared__ __align__(16) bf16_t L[2][4][8192];

  const int tid = threadIdx.x;
  const int wave = tid >> 6;
  const int lane = tid & 63;

  const int bid = blockIdx.x;
  const int x = bid & 7;
  const int j = bid >> 3;
  int tm, tn, ks;
  if (NKS > 1) {  // PV: per XCD 4tm x 4tn x 2ks
    ks = j >> 4;
    tm = (x << 2) | (j & 3);
    tn = (j >> 2) & 3;
  } else {        // per XCD 4tm x ntN, tm fast
    ks = 0;
    tm = (x << 2) | (j & 3);
    tn = j >> 2;
  }

  const bf16_t* Ab = A + (size_t)tm * (256 * LDK) + (size_t)ks * KEXT;
  const bf16_t* Bb = Bt + (size_t)tn * (256 * LDK) + (size_t)ks * KEXT;

  const int wr64 = (wave >> 2) * 64;
  const int wc32 = (wave & 3) * 32;
  const int fr = lane & 15;
  constexpr int nt = KEXT >> 6;

  f32x4 acc00[4][2], acc01[4][2], acc10[4][2], acc11[4][2];
#pragma unroll
  for (int m = 0; m < 4; ++m)
#pragma unroll
    for (int n = 0; n < 2; ++n) {
      acc00[m][n] = (f32x4){0.f, 0.f, 0.f, 0.f};
      acc01[m][n] = (f32x4){0.f, 0.f, 0.f, 0.f};
      acc10[m][n] = (f32x4){0.f, 0.f, 0.f, 0.f};
      acc11[m][n] = (f32x4){0.f, 0.f, 0.f, 0.f};
    }

  stage_half2<LDK>(Ab, &L[0][0][0], wave, lane);
  stage_half2<LDK>(Ab + (size_t)128 * LDK, &L[0][1][0], wave, lane);
  stage_half2<LDK>(Bb, &L[0][2][0], wave, lane);
  stage_half2<LDK>(Bb + (size_t)128 * LDK, &L[0][3][0], wave, lane);
  stage_half2<LDK>(Ab + 64, &L[1][0][0], wave, lane);
  stage_half2<LDK>(Bb + (size_t)128 * LDK + 64, &L[1][3][0], wave, lane);
  asm volatile("s_waitcnt vmcnt(4)" ::: "memory");
  __builtin_amdgcn_s_barrier();

  bf16x8 a[4][2], bA[2][2], bB[2][2];

#pragma unroll 1
  for (int t = 0; t < nt; ++t) {
    const int cur = t & 1;
    const bf16_t* A0h = &L[cur][0][0];
    const bf16_t* A1h = &L[cur][1][0];
    const bf16_t* B0h = &L[cur][2][0];
    const bf16_t* B1h = &L[cur][3][0];

#pragma unroll
    for (int m = 0; m < 4; ++m)
#pragma unroll
      for (int s = 0; s < 2; ++s)
        a[m][s] = ld_frag2(A0h, wr64 + m * 16 + fr, s, lane);
#pragma unroll
    for (int n = 0; n < 2; ++n)
#pragma unroll
      for (int s = 0; s < 2; ++s)
        bA[n][s] = ld_frag2(B0h, wc32 + n * 16 + fr, s, lane);
    if (t + 1 < nt)
      stage_half2<LDK>(Ab + (size_t)128 * LDK + (t + 1) * 64, &L[cur ^ 1][1][0],
                       wave, lane);
    __builtin_amdgcn_s_barrier();
    __builtin_amdgcn_s_setprio(1);
#pragma unroll
    for (int s = 0; s < 2; ++s)
#pragma unroll
      for (int m = 0; m < 4; ++m)
#pragma unroll
        for (int n = 0; n < 2; ++n)
          acc00[m][n] = __builtin_amdgcn_mfma_f32_16x16x32_bf16(a[m][s], bA[n][s],
                                                                acc00[m][n], 0, 0, 0);
    __builtin_amdgcn_s_setprio(0);
    __builtin_amdgcn_s_barrier();

#pragma unroll
    for (int n = 0; n < 2; ++n)
#pragma unroll
      for (int s = 0; s < 2; ++s)
        bB[n][s] = ld_frag2(B1h, wc32 + n * 16 + fr, s, lane);
    if (t + 1 < nt)
      stage_half2<LDK>(Bb + (t + 1) * 64, &L[cur ^ 1][2][0], wave, lane);
    __builtin_amdgcn_s_barrier();
    __builtin_amdgcn_s_setprio(1);
#pragma unroll
    for (int s = 0; s < 2; ++s)
#pragma unroll
      for (int m = 0; m < 4; ++m)
#pragma unroll
        for (int n = 0; n < 2; ++n)
          acc01[m][n] = __builtin_amdgcn_mfma_f32_16x16x32_bf16(a[m][s], bB[n][s],
                                                                acc01[m][n], 0, 0, 0);
    __builtin_amdgcn_s_setprio(0);
    __builtin_amdgcn_s_barrier();

#pragma unroll
    for (int m = 0; m < 4; ++m)
#pragma unroll
      for (int s = 0; s < 2; ++s)
        a[m][s] = ld_frag2(A1h, wr64 + m * 16 + fr, s, lane);
    if (t + 2 < nt)
      stage_half2<LDK>(Ab + (t + 2) * 64, &L[cur][0][0], wave, lane);
    __builtin_amdgcn_s_barrier();
    __builtin_amdgcn_s_setprio(1);
#pragma unroll
    for (int s = 0; s < 2; ++s)
#pragma unroll
      for (int m = 0; m < 4; ++m)
#pragma unroll
        for (int n = 0; n < 2; ++n)
          acc11[m][n] = __builtin_amdgcn_mfma_f32_16x16x32_bf16(a[m][s], bB[n][s],
                                                                acc11[m][n], 0, 0, 0);
    __builtin_amdgcn_s_setprio(0);
    __builtin_amdgcn_s_barrier();

    if (t + 2 < nt)
      stage_half2<LDK>(Bb + (size_t)128 * LDK + (t + 2) * 64, &L[cur][3][0],
                       wave, lane);
    __builtin_amdgcn_s_barrier();
    __builtin_amdgcn_s_setprio(1);
#pragma unroll
    for (int s = 0; s < 2; ++s)
#pragma unroll
      for (int m = 0; m < 4; ++m)
#pragma unroll
        for (int n = 0; n < 2; ++n)
          acc10[m][n] = __builtin_amdgcn_mfma_f32_16x16x32_bf16(a[m][s], bA[n][s],
                                                                acc10[m][n], 0, 0, 0);
    __builtin_amdgcn_s_setprio(0);
    if (t + 2 < nt)
      asm volatile("s_waitcnt vmcnt(4)" ::: "memory");
    else
      asm volatile("s_waitcnt vmcnt(0)" ::: "memory");
    __builtin_amdgcn_s_barrier();
  }

  const int fro = (lane >> 4) * 4;
#define STORE_QUAD(ACC, QM, QN)                                                  \
  _Pragma("unroll") for (int m = 0; m < 4; ++m) {                                \
    _Pragma("unroll") for (int n = 0; n < 2; ++n) {                              \
      const int row = tm * 256 + QM * 128 + wr64 + m * 16 + fro;                 \
      const int col = tn * 256 + QN * 128 + wc32 + n * 16 + fr;                  \
      if (EPI == 0) {                                                            \
        const float4 rv = *(const float4*)&rvec[row];                            \
        if (ks == 0) {                                                           \
          _Pragma("unroll") for (int jj = 0; jj < 4; ++jj)                       \
              Cf0[(size_t)(row + jj) * NN + col] =                               \
                  ACC[m][n][jj] * ((const float*)&rv)[jj];                       \
        } else {                                                                 \
          _Pragma("unroll") for (int jj = 0; jj < 4; ++jj)                       \
              Cf1b[(size_t)(row + jj) * NN + col] =                              \
                  (bf16_t)(ACC[m][n][jj] * ((const float*)&rv)[jj]);             \
        }                                                                        \
      } else {                                                                   \
        if (col < 1024) {                                                        \
          _Pragma("unroll") for (int jj = 0; jj < 4; ++jj) {                     \
            int pk = __builtin_amdgcn_cvt_pk_fp8_f32(ACC[m][n][jj],              \
                                                     ACC[m][n][jj], 0, false);   \
            qo[(size_t)(row + jj) * 1024 + col] = (uint8_t)pk;                   \
          }                                                                      \
        } else if (col < 2048) {                                                 \
          _Pragma("unroll") for (int jj = 0; jj < 4; ++jj) {                     \
            int pk = __builtin_amdgcn_cvt_pk_fp8_f32(ACC[m][n][jj],              \
                                                     ACC[m][n][jj], 0, false);   \
            ko[(size_t)(row + jj) * 1024 + (col - 1024)] = (uint8_t)pk;          \
          }                                                                      \
        } else {                                                                 \
          union { bf16_t h[4]; uint2 u; } tpk;                                   \
          _Pragma("unroll") for (int jj = 0; jj < 4; ++jj)                       \
              tpk.h[jj] = (bf16_t)ACC[m][n][jj];                                 \
          *(uint2*)&vtb[(size_t)(col - 2048) * MM + row] = tpk.u;                \
        }                                                                        \
      }                                                                          \
    }                                                                            \
  }
  STORE_QUAD(acc00, 0, 0)
  STORE_QUAD(acc01, 0, 1)
  STORE_QUAD(acc10, 1, 0)
  STORE_QUAD(acc11, 1, 1)
#undef STORE_QUAD
}

// ============== MX-fp8 scores GEMM, 256^2 tile, 8-wave 4-phase cadence ===========
// Same cadence/LDS geometry as gemm8p: each half = 128 rows x 128 B (BK=128 fp8)
// = 16 KB, identical staging/swizzle/barrier schedule. nt = 1024/128 = 8.
// K accumulation order per element identical to round-6 kernel (8 chained
// K=128 MFMAs) -> bitwise-identical S.

__device__ __forceinline__ void stage_half8(const uint8_t* g, uint8_t* lh,
                                            int wave, int lane) {
#pragma unroll
  for (int i = 0; i < 2; ++i) {
    const int ub = i * 8192 + wave * 1024;
    const int o = ub + lane * 16;
    const int row = o >> 7;                       // 128 B per row (BK=128 fp8)
    const int col = (o & 127) ^ ((row & 7) << 4); // inverse swizzle on source
    __builtin_amdgcn_global_load_lds((gv_t*)(g + (size_t)row * 1024 + col),
                                     (lv_t*)(lh + ub), 16, 0, 0);
  }
}

__device__ __forceinline__ i32x8 ld_frag8h(const uint8_t* h, int r, int lane) {
  const int sw = (r & 7) << 4;
  const int kg = (lane >> 4) * 32;
  const uint8_t* b = h + r * 128;
  i32x4 lo = *(const i32x4*)(b + (kg ^ sw));
  i32x4 hi = *(const i32x4*)(b + ((kg ^ sw) ^ 16));
  i32x8 v;
  v[0] = lo[0]; v[1] = lo[1]; v[2] = lo[2]; v[3] = lo[3];
  v[4] = hi[0]; v[5] = hi[1]; v[6] = hi[2]; v[7] = hi[3];
  return v;
}

__global__ __launch_bounds__(512) void scores8p(
    const uint8_t* __restrict__ qf, const uint8_t* __restrict__ kf,
    bf16_t* __restrict__ S, float* __restrict__ partial) {
  __shared__ __align__(16) uint8_t L[2][4][16384];  // [buf][A0,A1,B0,B1] 16 KB each

  const int tid = threadIdx.x;
  const int wave = tid >> 6;
  const int lane = tid & 63;

  // supertile: XCD x owns tm in [4x,4x+4), tm fast
  const int bid = blockIdx.x;
  const int x = bid & 7;
  const int j = bid >> 3;
  const int tm = (x << 2) | (j & 3);  // 0..31
  const int tn = j >> 2;              // 0..31

  const uint8_t* Ab = qf + (size_t)tm * 256 * 1024;
  const uint8_t* Bb = kf + (size_t)tn * 256 * 1024;

  const int wr64 = (wave >> 2) * 64;
  const int wc32 = (wave & 3) * 32;
  const int fr = lane & 15;
  constexpr int nt = 8;  // 1024 / 128

  f32x4 acc00[4][2], acc01[4][2], acc10[4][2], acc11[4][2];
#pragma unroll
  for (int m = 0; m < 4; ++m)
#pragma unroll
    for (int n = 0; n < 2; ++n) {
      acc00[m][n] = (f32x4){0.f, 0.f, 0.f, 0.f};
      acc01[m][n] = (f32x4){0.f, 0.f, 0.f, 0.f};
      acc10[m][n] = (f32x4){0.f, 0.f, 0.f, 0.f};
      acc11[m][n] = (f32x4){0.f, 0.f, 0.f, 0.f};
    }

  stage_half8(Ab, &L[0][0][0], wave, lane);
  stage_half8(Ab + (size_t)128 * 1024, &L[0][1][0], wave, lane);
  stage_half8(Bb, &L[0][2][0], wave, lane);
  stage_half8(Bb + (size_t)128 * 1024, &L[0][3][0], wave, lane);
  stage_half8(Ab + 128, &L[1][0][0], wave, lane);
  stage_half8(Bb + (size_t)128 * 1024 + 128, &L[1][3][0], wave, lane);
  asm volatile("s_waitcnt vmcnt(4)" ::: "memory");
  __builtin_amdgcn_s_barrier();

  i32x8 a[4], bA[2], bB[2];

#pragma unroll 1
  for (int t = 0; t < nt; ++t) {
    const int cur = t & 1;
    const uint8_t* A0h = &L[cur][0][0];
    const uint8_t* A1h = &L[cur][1][0];
    const uint8_t* B0h = &L[cur][2][0];
    const uint8_t* B1h = &L[cur][3][0];

    // -- phase 1: quadrant (0,0); stage A1(t+1)
#pragma unroll
    for (int m = 0; m < 4; ++m) a[m] = ld_frag8h(A0h, wr64 + m * 16 + fr, lane);
#pragma unroll
    for (int n = 0; n < 2; ++n) bA[n] = ld_frag8h(B0h, wc32 + n * 16 + fr, lane);
    if (t + 1 < nt)
      stage_half8(Ab + (size_t)128 * 1024 + (t + 1) * 128, &L[cur ^ 1][1][0],
                  wave, lane);
    __builtin_amdgcn_s_barrier();
    __builtin_amdgcn_s_setprio(1);
#pragma unroll
    for (int m = 0; m < 4; ++m)
#pragma unroll
      for (int n = 0; n < 2; ++n)
        acc00[m][n] = __builtin_amdgcn_mfma_scale_f32_16x16x128_f8f6f4(
            a[m], bA[n], acc00[m][n], 0, 0, 0, 0x7F7F7F7F, 0, 0x7F7F7F7F);
    __builtin_amdgcn_s_setprio(0);
    __builtin_amdgcn_s_barrier();

    // -- phase 2: quadrant (0,1); stage B0(t+1)
#pragma unroll
    for (int n = 0; n < 2; ++n) bB[n] = ld_frag8h(B1h, wc32 + n * 16 + fr, lane);
    if (t + 1 < nt)
      stage_half8(Bb + (t + 1) * 128, &L[cur ^ 1][2][0], wave, lane);
    __builtin_amdgcn_s_barrier();
    __builtin_amdgcn_s_setprio(1);
#pragma unroll
    for (int m = 0; m < 4; ++m)
#pragma unroll
      for (int n = 0; n < 2; ++n)
        acc01[m][n] = __builtin_amdgcn_mfma_scale_f32_16x16x128_f8f6f4(
            a[m], bB[n], acc01[m][n], 0, 0, 0, 0x7F7F7F7F, 0, 0x7F7F7F7F);
    __builtin_amdgcn_s_setprio(0);
    __builtin_amdgcn_s_barrier();

    // -- phase 3: quadrant (1,1); stage A0(t+2)
#pragma unroll
    for (int m = 0; m < 4; ++m) a[m] = ld_frag8h(A1h, wr64 + m * 16 + fr, lane);
    if (t + 2 < nt)
      stage_half8(Ab + (t + 2) * 128, &L[cur][0][0], wave, lane);
    __builtin_amdgcn_s_barrier();
    __builtin_amdgcn_s_setprio(1);
#pragma unroll
    for (int m = 0; m < 4; ++m)
#pragma unroll
      for (int n = 0; n < 2; ++n)
        acc11[m][n] = __builtin_amdgcn_mfma_scale_f32_16x16x128_f8f6f4(
            a[m], bB[n], acc11[m][n], 0, 0, 0, 0x7F7F7F7F, 0, 0x7F7F7F7F);
    __builtin_amdgcn_s_setprio(0);
    __builtin_amdgcn_s_barrier();

    // -- phase 4: quadrant (1,0); stage B1(t+2); boundary counted-vmcnt
    if (t + 2 < nt)
      stage_half8(Bb + (size_t)128 * 1024 + (t + 2) * 128, &L[cur][3][0],
                  wave, lane);
    __builtin_amdgcn_s_barrier();
    __builtin_amdgcn_s_setprio(1);
#pragma unroll
    for (int m = 0; m < 4; ++m)
#pragma unroll
      for (int n = 0; n < 2; ++n)
        acc10[m][n] = __builtin_amdgcn_mfma_scale_f32_16x16x128_f8f6f4(
            a[m], bA[n], acc10[m][n], 0, 0, 0, 0x7F7F7F7F, 0, 0x7F7F7F7F);
    __builtin_amdgcn_s_setprio(0);
    if (t + 2 < nt)
      asm volatile("s_waitcnt vmcnt(4)" ::: "memory");
    else
      asm volatile("s_waitcnt vmcnt(0)" ::: "memory");
    __builtin_amdgcn_s_barrier();
  }

  // Epilogue: exp, bf16 store, per-row partial sums (verified in rounds 4-5).
  const int fro = (lane >> 4) * 4;
#define EXPSTORE(ACC, QM, QN)                                                    \
  _Pragma("unroll") for (int m = 0; m < 4; ++m)                                  \
  _Pragma("unroll") for (int n = 0; n < 2; ++n)                                  \
  _Pragma("unroll") for (int jj = 0; jj < 4; ++jj) {                             \
    float e = __expf(ACC[m][n][jj]);                                             \
    ACC[m][n][jj] = e;                                                           \
    const int row = tm * 256 + QM * 128 + wr64 + m * 16 + fro + jj;              \
    const int col = tn * 256 + QN * 128 + wc32 + n * 16 + fr;                    \
    S[(size_t)row * 8192 + col] = (bf16_t)e;                                     \
  }
  EXPSTORE(acc00, 0, 0)
  EXPSTORE(acc01, 0, 1)
  EXPSTORE(acc10, 1, 0)
  EXPSTORE(acc11, 1, 1)
#undef EXPSTORE
  float* lsum = (float*)&L[0][0][0];  // 4 KB, LDS dead after K-loop
#define ROWSUM(A0, A1, QM)                                                       \
  _Pragma("unroll") for (int m = 0; m < 4; ++m) {                                \
    _Pragma("unroll") for (int jj = 0; jj < 4; ++jj) {                           \
      float s = A0[m][0][jj] + A0[m][1][jj] + A1[m][0][jj] + A1[m][1][jj];       \
      s += __shfl_xor(s, 1, 64);                                                 \
      s += __shfl_xor(s, 2, 64);                                                 \
      s += __shfl_xor(s, 4, 64);                                                 \
      s += __shfl_xor(s, 8, 64);                                                 \
      if (fr == 0) {                                                             \
        const int rl = QM * 128 + wr64 + m * 16 + fro + jj;                      \
        lsum[rl * 4 + (wave & 3)] = s;                                           \
      }                                                                          \
    }                                                                            \
  }
  ROWSUM(acc00, acc01, 0)
  ROWSUM(acc10, acc11, 1)
#undef ROWSUM
  __syncthreads();
  if (tid < 256) {
    float s = lsum[tid * 4] + lsum[tid * 4 + 1] + lsum[tid * 4 + 2] +
              lsum[tid * 4 + 3];
    partial[(size_t)tn * 8192 + tm * 256 + tid] = s;
  }
}

// ======================= converts, rowsum, add =======================
__global__ __launch_bounds__(256) void cvt_f32_bf16(const float* __restrict__ s,
                                                    bf16_t* __restrict__ d,
                                                    int n8, float scale) {
  int i = blockIdx.x * 256 + threadIdx.x;
  if (i >= n8) return;
  const float4* sp = (const float4*)s + (size_t)i * 2;
  float4 x0 = sp[0], x1 = sp[1];
  bf16x8 o;
  o[0] = (bf16_t)(x0.x * scale);
  o[1] = (bf16_t)(x0.y * scale);
  o[2] = (bf16_t)(x0.z * scale);
  o[3] = (bf16_t)(x0.w * scale);
  o[4] = (bf16_t)(x1.x * scale);
  o[5] = (bf16_t)(x1.y * scale);
  o[6] = (bf16_t)(x1.z * scale);
  o[7] = (bf16_t)(x1.w * scale);
  ((bf16x8*)d)[i] = o;
}

// r[row] = 1 / sum_tn partial[tn][row], tn = 0..31
__global__ __launch_bounds__(256) void rowsum_recip(const float* __restrict__ partial,
                                                    float* __restrict__ r) {
  int row = blockIdx.x * 256 + threadIdx.x;
  float s = 0.f;
#pragma unroll
  for (int t = 0; t < 32; ++t) s += partial[(size_t)t * 8192 + row];
  r[row] = 1.0f / s;
}

__global__ __launch_bounds__(256) void add_p1(float* __restrict__ out,
                                              const bf16_t* __restrict__ p1b) {
  size_t i = (size_t)blockIdx.x * 256 + threadIdx.x;
  bf16x8 b = ((const bf16x8*)p1b)[i];
  float4 a0 = ((const float4*)out)[i * 2];
  float4 a1 = ((const float4*)out)[i * 2 + 1];
  a0.x += (float)b[0];
  a0.y += (float)b[1];
  a0.z += (float)b[2];
  a0.w += (float)b[3];
  a1.x += (float)b[4];
  a1.y += (float)b[5];
  a1.z += (float)b[6];
  a1.w += (float)b[7];
  ((float4*)out)[i * 2] = a0;
  ((float4*)out)[i * 2 + 1] = a1;
}

extern "C" void kernel_launch(void* const* d_in, const int* in_sizes, int n_in,
                              void* d_out, int out_size, void* d_ws, size_t ws_size,
                              hipStream_t stream) {
  const int N = 8192, D = 1024;
  const float* x = (const float*)d_in[0];
  const float* Wq = (const float*)d_in[1];
  const float* Wk = (const float*)d_in[2];
  const float* Wv = (const float*)d_in[3];
  float* out = (float*)d_out;

  // Workspace layout:
  //   [0,8)    qf  fp8 [8192,1024]   } after scores: P1b bf16 [8192,1024] (16 MB)
  //   [8,16)   kf  fp8 [8192,1024]   }
  //   [16,32)  vt  bf16 [1024,8192]  (V^T)
  //   [32,160) S   bf16 [8192,8192]  (exp'd, unnormalized)
  //   [160,160.03) rvec f32 [8192]
  //   xb (16 MB) + Wb (6 MB) alias the start of S (dead before S written)
  //   partial f32 [32][8192] = 1 MB lives in d_out (dead until PV)
  uint8_t* qf = (uint8_t*)d_ws;
  uint8_t* kf = qf + (size_t)N * D;
  bf16_t* vt = (bf16_t*)(kf + (size_t)N * D);
  bf16_t* S = vt + (size_t)N * D;
  bf16_t* xb = S;
  bf16_t* Wb = xb + (size_t)N * D;
  bf16_t* P1b = (bf16_t*)d_ws;
  float* rvec = (float*)(S + (size_t)N * N);
  float* partial = out;

  const float sq = 0.1767766953f;  // 1/sqrt(32); folded into both Wq and Wk

  // 1) fp32 -> bf16 converts
  cvt_f32_bf16<<<(N * D / 8) / 256, 256, 0, stream>>>(x, xb, N * D / 8, 1.0f);
  cvt_f32_bf16<<<(D * D / 8) / 256, 256, 0, stream>>>(Wq, Wb, D * D / 8, sq);
  cvt_f32_bf16<<<(D * D / 8) / 256, 256, 0, stream>>>(Wk, Wb + (size_t)D * D,
                                                      D * D / 8, sq);
  cvt_f32_bf16<<<(D * D / 8) / 256, 256, 0, stream>>>(Wv, Wb + (size_t)2 * D * D,
                                                      D * D / 8, 1.0f);

  // 2) fused QKV: q,k -> fp8 e4m3; v -> vt bf16 (V^T)
  gemm8p<2, 8192, 3072, 1024, 1024, 1><<<(N / 256) * (3 * D / 256), 512, 0, stream>>>(
      xb, Wb, nullptr, nullptr, nullptr, qf, kf, vt);

  // 3) scores (MX-fp8, 256^2 8-phase): S = exp(q·k) + partial row sums
  scores8p<<<(N / 256) * (N / 256), 512, 0, stream>>>(qf, kf, S, partial);

  // 4) r[row] = 1 / sum(partial)
  rowsum_recip<<<N / 256, 256, 0, stream>>>(partial, rvec);

  // 5) out = (S @ vt^T) * r, split-K=2: ks0 -> out f32, ks1 -> P1b bf16
  gemm8p<0, 8192, 1024, 4096, 8192, 2><<<(N / 256) * (D / 256) * 2, 512, 0, stream>>>(
      S, vt, out, P1b, rvec, nullptr, nullptr, nullptr);

  // 6) out += P1b
  add_p1<<<(N * D / 8) / 256, 256, 0, stream>>>(out, P1b);
}